// Round 1
// baseline (1996.743 us; speedup 1.0000x reference)
//
#include <hip/hip_runtime.h>
#include <math.h>

#define ROI 84
#define WIN 12
#define HID 128
#define BATCH 64
#define SEQ (ROI * WIN)              // 1008
#define NNODE (BATCH * SEQ)          // 64512
#define NEDGE (NNODE * 16)           // 1032192
#define MAXDEG 64

// ---------------- CSR build ----------------

__global__ void k_zero_fill(int* fill) {
    int i = blockIdx.x * 256 + threadIdx.x;
    if (i < NNODE) fill[i] = 0;
}

__global__ void k_scatter(const int* __restrict__ ei, int* __restrict__ fill,
                          int* __restrict__ csr) {
    int e = blockIdx.x * 256 + threadIdx.x;
    if (e >= NEDGE) return;
    // Detect int64 vs int32 storage: int64 little-endian -> odd words are 0.
    bool is64 = true;
#pragma unroll
    for (int k = 0; k < 8; ++k) is64 = is64 && (ei[2 * k + 1] == 0);
    int s, d;
    if (is64) { s = ei[2 * e]; d = ei[2 * (NEDGE + e)]; }
    else      { s = ei[e];     d = ei[NEDGE + e]; }
    if (s < 0 || s >= NNODE || d < 0 || d >= NNODE) return;
    int pos = atomicAdd(&fill[d], 1);
    if (pos < MAXDEG) csr[d * MAXDEG + pos] = s;
}

// ---------------- GIN aggregation: out[n] = h[n] + sum_{j->n} h[j] ----------------

template <int D>
__global__ void k_agg(const float* __restrict__ h, const int* __restrict__ fill,
                      const int* __restrict__ csr, float* __restrict__ out) {
    int idx = blockIdx.x * 256 + threadIdx.x;
    if (idx >= NNODE * D) return;
    int n = idx / D;
    int f = idx - n * D;
    int deg = fill[n];
    if (deg > MAXDEG) deg = MAXDEG;
    const int* lst = csr + n * MAXDEG;
    float s = h[n * D + f];
    for (int j = 0; j < deg; ++j) s += h[lst[j] * D + f];
    out[idx] = s;
}

// ---------------- GEMM: out[N,128] = A[N,K] @ W[K,128] + bias (+pe) ----------------

template <int K, int KPAD, bool ADD_PE>
__global__ __launch_bounds__(256)
void k_gemm(const float* __restrict__ A, const float* __restrict__ W,
            const float* __restrict__ bias, const float* __restrict__ pe,
            float* __restrict__ out) {
    __shared__ float As[64 * KPAD];
    const int t = threadIdx.x;
    const int row0 = blockIdx.x * 64;

    if ((KPAD % 4) == 0 && (K % 4) == 0) {
        const int KF = K / 4;
        for (int i = t; i < 64 * KF; i += 256) {
            int r = i / KF, c4 = i - r * KF;
            *(float4*)&As[r * KPAD + c4 * 4] =
                *(const float4*)&A[(size_t)(row0 + r) * K + c4 * 4];
        }
    } else {
        for (int i = t; i < 64 * K; i += 256) {
            int r = i / K, c = i - r * K;
            As[r * KPAD + c] = A[(size_t)(row0 + r) * K + c];
        }
    }
    __syncthreads();

    const int r0 = (t >> 4) << 2;      // 16 groups * 4 rows
    const int c0 = (t & 15) << 3;      // 16 groups * 8 cols
    float acc[4][8];
#pragma unroll
    for (int i = 0; i < 4; ++i)
#pragma unroll
        for (int j = 0; j < 8; ++j) acc[i][j] = 0.f;

#pragma unroll 4
    for (int k = 0; k < K; ++k) {
        float4 w0 = *(const float4*)&W[k * 128 + c0];
        float4 w1 = *(const float4*)&W[k * 128 + c0 + 4];
#pragma unroll
        for (int i = 0; i < 4; ++i) {
            float a = As[(r0 + i) * KPAD + k];
            acc[i][0] += a * w0.x; acc[i][1] += a * w0.y;
            acc[i][2] += a * w0.z; acc[i][3] += a * w0.w;
            acc[i][4] += a * w1.x; acc[i][5] += a * w1.y;
            acc[i][6] += a * w1.z; acc[i][7] += a * w1.w;
        }
    }

    float4 b0 = *(const float4*)&bias[c0];
    float4 b1 = *(const float4*)&bias[c0 + 4];
#pragma unroll
    for (int i = 0; i < 4; ++i) {
        int gr = row0 + r0 + i;
        float4 o0, o1;
        o0.x = acc[i][0] + b0.x; o0.y = acc[i][1] + b0.y;
        o0.z = acc[i][2] + b0.z; o0.w = acc[i][3] + b0.w;
        o1.x = acc[i][4] + b1.x; o1.y = acc[i][5] + b1.y;
        o1.z = acc[i][6] + b1.z; o1.w = acc[i][7] + b1.w;
        if (ADD_PE) {
            const float* pp = pe + (size_t)(gr % SEQ) * 128;
            float4 p0 = *(const float4*)&pp[c0];
            float4 p1 = *(const float4*)&pp[c0 + 4];
            o0.x += p0.x; o0.y += p0.y; o0.z += p0.z; o0.w += p0.w;
            o1.x += p1.x; o1.y += p1.y; o1.z += p1.z; o1.w += p1.w;
        }
        *(float4*)&out[(size_t)gr * 128 + c0] = o0;
        *(float4*)&out[(size_t)gr * 128 + c0 + 4] = o1;
    }
}

// ---------------- flash self-attention (q = k = v), per batch ----------------
// TQ=64 query rows/block, TK=48 key rows/tile (1008 = 21*48 exactly)

#define TQ 64
#define TK 48
#define NKT 21
#define QPAD 132
#define SPAD 52

__global__ __launch_bounds__(256)
void k_flash(const float* __restrict__ q, float* __restrict__ ctx) {
    __shared__ float Qs[TQ * QPAD];
    __shared__ float Ks[TK * QPAD];
    __shared__ float Ss[TQ * SPAD];
    __shared__ float mL[TQ], lL[TQ], aL[TQ];

    const int t = threadIdx.x;
    const int b = blockIdx.x >> 4;
    const int qt = blockIdx.x & 15;
    const int qrow0 = qt * TQ;
    const float* qb = q + (size_t)b * SEQ * HID;

    // stage Q tile (zeros for rows >= SEQ)
    {
        int r = t >> 2, seg = (t & 3) * 32;
        bool valid = (qrow0 + r) < SEQ;
#pragma unroll
        for (int i = 0; i < 8; ++i) {
            float4 v = valid ? *(const float4*)&qb[(size_t)(qrow0 + r) * HID + seg + i * 4]
                             : make_float4(0.f, 0.f, 0.f, 0.f);
            *(float4*)&Qs[r * QPAD + seg + i * 4] = v;
        }
    }
    if (t < TQ) { mL[t] = -INFINITY; lL[t] = 0.f; }

    float O[4][8];
#pragma unroll
    for (int i = 0; i < 4; ++i)
#pragma unroll
        for (int j = 0; j < 8; ++j) O[i][j] = 0.f;

    const float scale = 0.08838834764831845f;  // 1/sqrt(128)
    const int rA0 = (t >> 4) << 2;   // rows for phases A/C (4 per thread)
    const int cA0 = (t & 15) * 3;    // score cols for phase A (3 per thread)
    const int cC0 = (t & 15) << 3;   // out cols for phase C (8 per thread)
    const int rB = t >> 2;           // row for phase B
    const int jB = t & 3;

    for (int kt = 0; kt < NKT; ++kt) {
        __syncthreads();  // protect Ks/Ss from previous iteration's readers
        if (t < 192) {    // stage K tile: 48 rows x 128
            int r = t >> 2, seg = (t & 3) * 32;
            int grow = kt * TK + r;
#pragma unroll
            for (int i = 0; i < 8; ++i)
                *(float4*)&Ks[r * QPAD + seg + i * 4] =
                    *(const float4*)&qb[(size_t)grow * HID + seg + i * 4];
        }
        __syncthreads();

        // ---- phase A: S = scale * Q K^T  (4x3 micro-tile) ----
        float sa[4][3];
#pragma unroll
        for (int i = 0; i < 4; ++i)
#pragma unroll
            for (int j = 0; j < 3; ++j) sa[i][j] = 0.f;

#pragma unroll 2
        for (int d0 = 0; d0 < HID; d0 += 4) {
            float4 qv[4], kv[3];
#pragma unroll
            for (int i = 0; i < 4; ++i) qv[i] = *(const float4*)&Qs[(rA0 + i) * QPAD + d0];
#pragma unroll
            for (int j = 0; j < 3; ++j) kv[j] = *(const float4*)&Ks[(cA0 + j) * QPAD + d0];
#pragma unroll
            for (int i = 0; i < 4; ++i)
#pragma unroll
                for (int j = 0; j < 3; ++j)
                    sa[i][j] += qv[i].x * kv[j].x + qv[i].y * kv[j].y +
                                qv[i].z * kv[j].z + qv[i].w * kv[j].w;
        }
#pragma unroll
        for (int i = 0; i < 4; ++i)
#pragma unroll
            for (int j = 0; j < 3; ++j)
                Ss[(rA0 + i) * SPAD + cA0 + j] = sa[i][j] * scale;
        __syncthreads();

        // ---- phase B: online softmax update (4 threads per row) ----
        {
            float tmax = -INFINITY;
            for (int c = jB; c < TK; c += 4) tmax = fmaxf(tmax, Ss[rB * SPAD + c]);
            tmax = fmaxf(tmax, __shfl_xor(tmax, 1));
            tmax = fmaxf(tmax, __shfl_xor(tmax, 2));
            float mold = mL[rB];
            float mnew = fmaxf(mold, tmax);
            float alpha = __expf(mold - mnew);
            float psum = 0.f;
            for (int c = jB; c < TK; c += 4) {
                float p = __expf(Ss[rB * SPAD + c] - mnew);
                Ss[rB * SPAD + c] = p;
                psum += p;
            }
            psum += __shfl_xor(psum, 1);
            psum += __shfl_xor(psum, 2);
            if (jB == 0) {
                lL[rB] = lL[rB] * alpha + psum;
                mL[rB] = mnew;
                aL[rB] = alpha;
            }
        }
        __syncthreads();

        // ---- phase C: O = O*alpha + P @ V  (V = K tile) ----
#pragma unroll
        for (int i = 0; i < 4; ++i) {
            float a = aL[rA0 + i];
#pragma unroll
            for (int j = 0; j < 8; ++j) O[i][j] *= a;
        }
        for (int k0 = 0; k0 < TK; k0 += 4) {
            float4 pv[4];
#pragma unroll
            for (int i = 0; i < 4; ++i) pv[i] = *(const float4*)&Ss[(rA0 + i) * SPAD + k0];
#pragma unroll
            for (int kk = 0; kk < 4; ++kk) {
                float4 v0 = *(const float4*)&Ks[(k0 + kk) * QPAD + cC0];
                float4 v1 = *(const float4*)&Ks[(k0 + kk) * QPAD + cC0 + 4];
#pragma unroll
                for (int i = 0; i < 4; ++i) {
                    float p = (kk == 0) ? pv[i].x : (kk == 1) ? pv[i].y
                            : (kk == 2) ? pv[i].z : pv[i].w;
                    O[i][0] += p * v0.x; O[i][1] += p * v0.y;
                    O[i][2] += p * v0.z; O[i][3] += p * v0.w;
                    O[i][4] += p * v1.x; O[i][5] += p * v1.y;
                    O[i][6] += p * v1.z; O[i][7] += p * v1.w;
                }
            }
        }
    }

    // ---- finalize: O / l, write ctx ----
#pragma unroll
    for (int i = 0; i < 4; ++i) {
        int r = rA0 + i;
        int gr = qrow0 + r;
        if (gr < SEQ) {
            float inv = 1.f / lL[r];
            float4 o0, o1;
            o0.x = O[i][0] * inv; o0.y = O[i][1] * inv;
            o0.z = O[i][2] * inv; o0.w = O[i][3] * inv;
            o1.x = O[i][4] * inv; o1.y = O[i][5] * inv;
            o1.z = O[i][6] * inv; o1.w = O[i][7] * inv;
            size_t base = ((size_t)b * SEQ + gr) * HID;
            *(float4*)&ctx[base + cC0] = o0;
            *(float4*)&ctx[base + cC0 + 4] = o1;
        }
    }
}

// ---------------- pooling: [B, WIN, 4*HID] features ----------------

__global__ void k_pool(const float* __restrict__ t1, const float* __restrict__ ctx,
                       float* __restrict__ aggr) {
    int bw = blockIdx.x;              // B*WIN = 768
    int b = bw / WIN, w = bw - b * WIN;
    int c = threadIdx.x;              // 128
    const float* p1 = t1 + ((size_t)(b * SEQ + w * ROI)) * HID + c;
    const float* p2 = ctx + ((size_t)(b * SEQ + w * ROI)) * HID + c;
    float mx1 = -INFINITY, sm1 = 0.f, mx2 = -INFINITY, sm2 = 0.f;
    for (int r = 0; r < ROI; ++r) {
        float a = p1[r * HID]; mx1 = fmaxf(mx1, a); sm1 += a;
        float d = p2[r * HID]; mx2 = fmaxf(mx2, d); sm2 += d;
    }
    float* o = aggr + (size_t)b * 6144 + w * 512;
    o[c] = mx1;
    o[128 + c] = sm1 * (1.f / 84.f);
    o[256 + c] = mx2;
    o[384 + c] = sm2 * (1.f / 84.f);
}

// ---------------- fc1 + silu + bn1: [64,6144]@[6144,512] ----------------

__global__ __launch_bounds__(256)
void k_fc1(const float* __restrict__ aggr, const float* __restrict__ W,
           const float* __restrict__ bias,
           const float* __restrict__ g, const float* __restrict__ bb,
           const float* __restrict__ m, const float* __restrict__ v,
           float* __restrict__ h1) {
    __shared__ float As[64 * 132];
    const int t = threadIdx.x;
    const int cb = blockIdx.x * 64;   // 8 blocks cover 512 cols
    const int r0 = (t >> 4) << 2;
    const int c0 = (t & 15) << 2;
    float acc[4][4];
#pragma unroll
    for (int i = 0; i < 4; ++i)
#pragma unroll
        for (int j = 0; j < 4; ++j) acc[i][j] = 0.f;

    for (int kb = 0; kb < 6144; kb += 128) {
        __syncthreads();
        {
            int r = t >> 2, seg = (t & 3) * 32;
#pragma unroll
            for (int i = 0; i < 8; ++i)
                *(float4*)&As[r * 132 + seg + i * 4] =
                    *(const float4*)&aggr[(size_t)r * 6144 + kb + seg + i * 4];
        }
        __syncthreads();
#pragma unroll 4
        for (int kk = 0; kk < 128; ++kk) {
            float4 w = *(const float4*)&W[(size_t)(kb + kk) * 512 + cb + c0];
#pragma unroll
            for (int i = 0; i < 4; ++i) {
                float a = As[(r0 + i) * 132 + kk];
                acc[i][0] += a * w.x; acc[i][1] += a * w.y;
                acc[i][2] += a * w.z; acc[i][3] += a * w.w;
            }
        }
    }
#pragma unroll
    for (int i = 0; i < 4; ++i) {
        int row = r0 + i;
#pragma unroll
        for (int j = 0; j < 4; ++j) {
            int c = cb + c0 + j;
            float x = acc[i][j] + bias[c];
            float s = x / (1.f + __expf(-x));                       // silu
            float y = (s - m[c]) * rsqrtf(v[c] + 1e-5f) * g[c] + bb[c];  // bn1
            h1[(size_t)row * 512 + c] = y;
        }
    }
}

// ---------------- head: fc2+silu+bn2 -> fc3 -> softmax ----------------

__global__ __launch_bounds__(256)
void k_head(const float* __restrict__ h1,
            const float* __restrict__ fc2w, const float* __restrict__ fc2b,
            const float* __restrict__ g2, const float* __restrict__ b2,
            const float* __restrict__ m2, const float* __restrict__ v2,
            const float* __restrict__ fc3w, const float* __restrict__ fc3b,
            float* __restrict__ out) {
    __shared__ float row[512];
    __shared__ float red[8 * 32];
    __shared__ float h2[32];
    const int b = blockIdx.x, t = threadIdx.x;
    row[t] = h1[(size_t)b * 512 + t];
    row[t + 256] = h1[(size_t)b * 512 + 256 + t];
    __syncthreads();
    {
        int c = t & 31, part = t >> 5;
        float s = 0.f;
        for (int k = part * 64; k < part * 64 + 64; ++k) s += row[k] * fc2w[k * 32 + c];
        red[part * 32 + c] = s;
    }
    __syncthreads();
    if (t < 32) {
        float vv = 0.f;
        for (int p = 0; p < 8; ++p) vv += red[p * 32 + t];
        vv += fc2b[t];
        float sl = vv / (1.f + __expf(-vv));
        h2[t] = (sl - m2[t]) * rsqrtf(v2[t] + 1e-5f) * g2[t] + b2[t];
    }
    __syncthreads();
    if (t == 0) {
        float l0 = fc3b[0], l1 = fc3b[1];
        for (int k = 0; k < 32; ++k) { l0 += h2[k] * fc3w[k * 2]; l1 += h2[k] * fc3w[k * 2 + 1]; }
        float mx = fmaxf(l0, l1);
        float e0 = __expf(l0 - mx), e1 = __expf(l1 - mx);
        float inv = 1.f / (e0 + e1);
        out[b * 2] = e0 * inv;
        out[b * 2 + 1] = e1 * inv;
    }
}

// ---------------- launch ----------------

extern "C" void kernel_launch(void* const* d_in, const int* in_sizes, int n_in,
                              void* d_out, int out_size, void* d_ws, size_t ws_size,
                              hipStream_t stream) {
    (void)in_sizes; (void)n_in; (void)out_size;

    const float* x    = (const float*)d_in[0];
    const int*   ei   = (const int*)d_in[1];
    const float* pe   = (const float*)d_in[2];
    const float* W1   = (const float*)d_in[3];
    const float* b1   = (const float*)d_in[4];
    const float* W2   = (const float*)d_in[5];
    const float* b2   = (const float*)d_in[6];
    const float* fc1w = (const float*)d_in[7];
    const float* fc1b = (const float*)d_in[8];
    const float* fc2w = (const float*)d_in[9];
    const float* fc2b = (const float*)d_in[10];
    const float* fc3w = (const float*)d_in[11];
    const float* fc3b = (const float*)d_in[12];
    const float* bn1g = (const float*)d_in[13];
    const float* bn1b = (const float*)d_in[14];
    const float* bn1m = (const float*)d_in[15];
    const float* bn1v = (const float*)d_in[16];
    const float* bn2g = (const float*)d_in[17];
    const float* bn2b = (const float*)d_in[18];
    const float* bn2m = (const float*)d_in[19];
    const float* bn2v = (const float*)d_in[20];
    float* out = (float*)d_out;

    char* ws = (char*)d_ws;
    float* A1   = (float*)(ws + 0);            // N*84*4  = 21,676,032
    float* t1   = (float*)(ws + 21676032);     // N*128*4 = 33,030,144
    float* A2   = (float*)(ws + 54706176);     // 33,030,144
    float* q    = (float*)(ws + 87736320);     // 33,030,144
    float* ctx  = (float*)(ws + 120766464);    // 33,030,144
    float* aggr = (float*)(ws + 153796608);    // 64*6144*4 = 1,572,864
    float* h1   = (float*)(ws + 155369472);    // 64*512*4  = 131,072
    int*   fill = (int*)  (ws + 155500544);    // N*4 = 258,048
    int*   csr  = (int*)  (ws + 155758592);    // N*64*4 = 16,515,072
    // total = 172,273,664 bytes
    if (ws_size < 172273664ull) return;

    k_zero_fill<<<(NNODE + 255) / 256, 256, 0, stream>>>(fill);
    k_scatter<<<(NEDGE + 255) / 256, 256, 0, stream>>>(ei, fill, csr);
    k_agg<84><<<(NNODE * 84 + 255) / 256, 256, 0, stream>>>(x, fill, csr, A1);
    k_gemm<84, 85, false><<<NNODE / 64, 256, 0, stream>>>(A1, W1, b1, nullptr, t1);
    k_agg<128><<<(NNODE * 128) / 256, 256, 0, stream>>>(t1, fill, csr, A2);
    k_gemm<128, 132, true><<<NNODE / 64, 256, 0, stream>>>(A2, W2, b2, pe, q);
    k_flash<<<BATCH * 16, 256, 0, stream>>>(q, ctx);
    k_pool<<<BATCH * WIN, 128, 0, stream>>>(t1, ctx, aggr);
    k_fc1<<<8, 256, 0, stream>>>(aggr, fc1w, fc1b, bn1g, bn1b, bn1m, bn1v, h1);
    k_head<<<BATCH, 256, 0, stream>>>(h1, fc2w, fc2b, bn2g, bn2b, bn2m, bn2v,
                                      fc3w, fc3b, out);
}

// Round 3
// 1011.711 us; speedup vs baseline: 1.9736x; 1.9736x over previous
//
#include <hip/hip_runtime.h>
#include <math.h>

#define ROI 84
#define WIN 12
#define HID 128
#define BATCH 64
#define SEQ (ROI * WIN)              // 1008
#define NNODE (BATCH * SEQ)          // 64512
#define NEDGE (NNODE * 16)           // 1032192
#define MAXDEG 64

// ---------------- CSR build ----------------

__global__ void k_zero_fill(int* fill) {
    int i = blockIdx.x * 256 + threadIdx.x;
    if (i < NNODE) fill[i] = 0;
}

__global__ void k_scatter(const int* __restrict__ ei, int* __restrict__ fill,
                          int* __restrict__ csr) {
    int e = blockIdx.x * 256 + threadIdx.x;
    if (e >= NEDGE) return;
    // Detect int64 vs int32 storage: int64 little-endian -> odd words are 0.
    bool is64 = true;
#pragma unroll
    for (int k = 0; k < 8; ++k) is64 = is64 && (ei[2 * k + 1] == 0);
    int s, d;
    if (is64) { s = ei[2 * e]; d = ei[2 * (NEDGE + e)]; }
    else      { s = ei[e];     d = ei[NEDGE + e]; }
    if (s < 0 || s >= NNODE || d < 0 || d >= NNODE) return;
    int pos = atomicAdd(&fill[d], 1);
    if (pos < MAXDEG) csr[d * MAXDEG + pos] = s;
}

// ---------------- GIN aggregation (float4): out[n] = h[n] + sum_{j->n} h[j] ----
// D4 = float4s per row (21 for D=84, 32 for D=128). Row byte stride is a
// multiple of 16 in both cases so float4 views stay aligned.

template <int D4>
__global__ void k_agg4(const float4* __restrict__ h, const int* __restrict__ fill,
                       const int* __restrict__ csr, float4* __restrict__ out) {
    int idx = blockIdx.x * 256 + threadIdx.x;
    if (idx >= NNODE * D4) return;
    int n = idx / D4;
    int f = idx - n * D4;
    int deg = fill[n];
    if (deg > MAXDEG) deg = MAXDEG;
    const int* lst = csr + n * MAXDEG;
    float4 s = h[(size_t)n * D4 + f];
    int j = 0;
    for (; j + 2 <= deg; j += 2) {
        float4 v0 = h[(size_t)lst[j] * D4 + f];
        float4 v1 = h[(size_t)lst[j + 1] * D4 + f];
        s.x += v0.x + v1.x; s.y += v0.y + v1.y;
        s.z += v0.z + v1.z; s.w += v0.w + v1.w;
    }
    if (j < deg) {
        float4 v0 = h[(size_t)lst[j] * D4 + f];
        s.x += v0.x; s.y += v0.y; s.z += v0.z; s.w += v0.w;
    }
    out[idx] = s;
}

// ---------------- GEMM: out[N,128] = A[N,K] @ W[K,128] + bias (+pe) ----------------

template <int K, int KPAD, bool ADD_PE>
__global__ __launch_bounds__(256)
void k_gemm(const float* __restrict__ A, const float* __restrict__ W,
            const float* __restrict__ bias, const float* __restrict__ pe,
            float* __restrict__ out) {
    __shared__ float As[64 * KPAD];
    const int t = threadIdx.x;
    const int row0 = blockIdx.x * 64;

    if ((KPAD % 4) == 0 && (K % 4) == 0) {
        const int KF = K / 4;
        for (int i = t; i < 64 * KF; i += 256) {
            int r = i / KF, c4 = i - r * KF;
            *(float4*)&As[r * KPAD + c4 * 4] =
                *(const float4*)&A[(size_t)(row0 + r) * K + c4 * 4];
        }
    } else {
        for (int i = t; i < 64 * K; i += 256) {
            int r = i / K, c = i - r * K;
            As[r * KPAD + c] = A[(size_t)(row0 + r) * K + c];
        }
    }
    __syncthreads();

    const int r0 = (t >> 4) << 2;      // 16 groups * 4 rows
    const int c0 = (t & 15) << 3;      // 16 groups * 8 cols
    float acc[4][8];
#pragma unroll
    for (int i = 0; i < 4; ++i)
#pragma unroll
        for (int j = 0; j < 8; ++j) acc[i][j] = 0.f;

#pragma unroll 4
    for (int k = 0; k < K; ++k) {
        float4 w0 = *(const float4*)&W[k * 128 + c0];
        float4 w1 = *(const float4*)&W[k * 128 + c0 + 4];
#pragma unroll
        for (int i = 0; i < 4; ++i) {
            float a = As[(r0 + i) * KPAD + k];
            acc[i][0] += a * w0.x; acc[i][1] += a * w0.y;
            acc[i][2] += a * w0.z; acc[i][3] += a * w0.w;
            acc[i][4] += a * w1.x; acc[i][5] += a * w1.y;
            acc[i][6] += a * w1.z; acc[i][7] += a * w1.w;
        }
    }

    float4 b0 = *(const float4*)&bias[c0];
    float4 b1 = *(const float4*)&bias[c0 + 4];
#pragma unroll
    for (int i = 0; i < 4; ++i) {
        int gr = row0 + r0 + i;
        float4 o0, o1;
        o0.x = acc[i][0] + b0.x; o0.y = acc[i][1] + b0.y;
        o0.z = acc[i][2] + b0.z; o0.w = acc[i][3] + b0.w;
        o1.x = acc[i][4] + b1.x; o1.y = acc[i][5] + b1.y;
        o1.z = acc[i][6] + b1.z; o1.w = acc[i][7] + b1.w;
        if (ADD_PE) {
            const float* pp = pe + (size_t)(gr % SEQ) * 128;
            float4 p0 = *(const float4*)&pp[c0];
            float4 p1 = *(const float4*)&pp[c0 + 4];
            o0.x += p0.x; o0.y += p0.y; o0.z += p0.z; o0.w += p0.w;
            o1.x += p1.x; o1.y += p1.y; o1.z += p1.z; o1.w += p1.w;
        }
        *(float4*)&out[(size_t)gr * 128 + c0] = o0;
        *(float4*)&out[(size_t)gr * 128 + c0 + 4] = o1;
    }
}

// ---------------- flash self-attention (q = k = v), per batch ----------------
// TQ=64 query rows/block, TK=48 key rows/tile (1008 = 21*48 exactly)

#define TQ 64
#define TK 48
#define NKT 21
#define QPAD 132
#define SPAD 52

__global__ __launch_bounds__(256)
void k_flash(const float* __restrict__ q, float* __restrict__ ctx) {
    __shared__ float Qs[TQ * QPAD];
    __shared__ float Ks[TK * QPAD];
    __shared__ float Ss[TQ * SPAD];
    __shared__ float mL[TQ], lL[TQ], aL[TQ];

    const int t = threadIdx.x;
    const int b = blockIdx.x >> 4;
    const int qt = blockIdx.x & 15;
    const int qrow0 = qt * TQ;
    const float* qb = q + (size_t)b * SEQ * HID;

    // stage Q tile (zeros for rows >= SEQ)
    {
        int r = t >> 2, seg = (t & 3) * 32;
        bool valid = (qrow0 + r) < SEQ;
#pragma unroll
        for (int i = 0; i < 8; ++i) {
            float4 v = valid ? *(const float4*)&qb[(size_t)(qrow0 + r) * HID + seg + i * 4]
                             : make_float4(0.f, 0.f, 0.f, 0.f);
            *(float4*)&Qs[r * QPAD + seg + i * 4] = v;
        }
    }
    if (t < TQ) { mL[t] = -INFINITY; lL[t] = 0.f; }

    float O[4][8];
#pragma unroll
    for (int i = 0; i < 4; ++i)
#pragma unroll
        for (int j = 0; j < 8; ++j) O[i][j] = 0.f;

    const float scale = 0.08838834764831845f;  // 1/sqrt(128)
    const int rA0 = (t >> 4) << 2;   // rows for phases A/C (4 per thread)
    const int cA0 = (t & 15) * 3;    // score cols for phase A (3 per thread)
    const int cC0 = (t & 15) << 3;   // out cols for phase C (8 per thread)
    const int rB = t >> 2;           // row for phase B
    const int jB = t & 3;

    for (int kt = 0; kt < NKT; ++kt) {
        __syncthreads();  // protect Ks/Ss from previous iteration's readers
        if (t < 192) {    // stage K tile: 48 rows x 128
            int r = t >> 2, seg = (t & 3) * 32;
            int grow = kt * TK + r;
#pragma unroll
            for (int i = 0; i < 8; ++i)
                *(float4*)&Ks[r * QPAD + seg + i * 4] =
                    *(const float4*)&qb[(size_t)grow * HID + seg + i * 4];
        }
        __syncthreads();

        // ---- phase A: S = scale * Q K^T  (4x3 micro-tile) ----
        float sa[4][3];
#pragma unroll
        for (int i = 0; i < 4; ++i)
#pragma unroll
            for (int j = 0; j < 3; ++j) sa[i][j] = 0.f;

#pragma unroll 2
        for (int d0 = 0; d0 < HID; d0 += 4) {
            float4 qv[4], kv[3];
#pragma unroll
            for (int i = 0; i < 4; ++i) qv[i] = *(const float4*)&Qs[(rA0 + i) * QPAD + d0];
#pragma unroll
            for (int j = 0; j < 3; ++j) kv[j] = *(const float4*)&Ks[(cA0 + j) * QPAD + d0];
#pragma unroll
            for (int i = 0; i < 4; ++i)
#pragma unroll
                for (int j = 0; j < 3; ++j)
                    sa[i][j] += qv[i].x * kv[j].x + qv[i].y * kv[j].y +
                                qv[i].z * kv[j].z + qv[i].w * kv[j].w;
        }
#pragma unroll
        for (int i = 0; i < 4; ++i)
#pragma unroll
            for (int j = 0; j < 3; ++j)
                Ss[(rA0 + i) * SPAD + cA0 + j] = sa[i][j] * scale;
        __syncthreads();

        // ---- phase B: online softmax update (4 threads per row) ----
        {
            float tmax = -INFINITY;
            for (int c = jB; c < TK; c += 4) tmax = fmaxf(tmax, Ss[rB * SPAD + c]);
            tmax = fmaxf(tmax, __shfl_xor(tmax, 1));
            tmax = fmaxf(tmax, __shfl_xor(tmax, 2));
            float mold = mL[rB];
            float mnew = fmaxf(mold, tmax);
            float alpha = __expf(mold - mnew);
            float psum = 0.f;
            for (int c = jB; c < TK; c += 4) {
                float p = __expf(Ss[rB * SPAD + c] - mnew);
                Ss[rB * SPAD + c] = p;
                psum += p;
            }
            psum += __shfl_xor(psum, 1);
            psum += __shfl_xor(psum, 2);
            if (jB == 0) {
                lL[rB] = lL[rB] * alpha + psum;
                mL[rB] = mnew;
                aL[rB] = alpha;
            }
        }
        __syncthreads();

        // ---- phase C: O = O*alpha + P @ V  (V = K tile) ----
#pragma unroll
        for (int i = 0; i < 4; ++i) {
            float a = aL[rA0 + i];
#pragma unroll
            for (int j = 0; j < 8; ++j) O[i][j] *= a;
        }
        for (int k0 = 0; k0 < TK; k0 += 4) {
            float4 pv[4];
#pragma unroll
            for (int i = 0; i < 4; ++i) pv[i] = *(const float4*)&Ss[(rA0 + i) * SPAD + k0];
#pragma unroll
            for (int kk = 0; kk < 4; ++kk) {
                float4 v0 = *(const float4*)&Ks[(k0 + kk) * QPAD + cC0];
                float4 v1 = *(const float4*)&Ks[(k0 + kk) * QPAD + cC0 + 4];
#pragma unroll
                for (int i = 0; i < 4; ++i) {
                    float p = (kk == 0) ? pv[i].x : (kk == 1) ? pv[i].y
                            : (kk == 2) ? pv[i].z : pv[i].w;
                    O[i][0] += p * v0.x; O[i][1] += p * v0.y;
                    O[i][2] += p * v0.z; O[i][3] += p * v0.w;
                    O[i][4] += p * v1.x; O[i][5] += p * v1.y;
                    O[i][6] += p * v1.z; O[i][7] += p * v1.w;
                }
            }
        }
    }

    // ---- finalize: O / l, write ctx ----
#pragma unroll
    for (int i = 0; i < 4; ++i) {
        int r = rA0 + i;
        int gr = qrow0 + r;
        if (gr < SEQ) {
            float inv = 1.f / lL[r];
            float4 o0, o1;
            o0.x = O[i][0] * inv; o0.y = O[i][1] * inv;
            o0.z = O[i][2] * inv; o0.w = O[i][3] * inv;
            o1.x = O[i][4] * inv; o1.y = O[i][5] * inv;
            o1.z = O[i][6] * inv; o1.w = O[i][7] * inv;
            size_t base = ((size_t)b * SEQ + gr) * HID;
            *(float4*)&ctx[base + cC0] = o0;
            *(float4*)&ctx[base + cC0 + 4] = o1;
        }
    }
}

// ---------------- pooling: [B, WIN, 4*HID] features ----------------

__global__ void k_pool(const float* __restrict__ t1, const float* __restrict__ ctx,
                       float* __restrict__ aggr) {
    int bw = blockIdx.x;              // B*WIN = 768
    int b = bw / WIN, w = bw - b * WIN;
    int c = threadIdx.x;              // 128
    const float* p1 = t1 + ((size_t)(b * SEQ + w * ROI)) * HID + c;
    const float* p2 = ctx + ((size_t)(b * SEQ + w * ROI)) * HID + c;
    float mx1 = -INFINITY, sm1 = 0.f, mx2 = -INFINITY, sm2 = 0.f;
    for (int r = 0; r < ROI; ++r) {
        float a = p1[r * HID]; mx1 = fmaxf(mx1, a); sm1 += a;
        float d = p2[r * HID]; mx2 = fmaxf(mx2, d); sm2 += d;
    }
    float* o = aggr + (size_t)b * 6144 + w * 512;
    o[c] = mx1;
    o[128 + c] = sm1 * (1.f / 84.f);
    o[256 + c] = mx2;
    o[384 + c] = sm2 * (1.f / 84.f);
}

// ---------------- fc1 split-K: partial GEMM [64,6144]@[6144,512] ----------------
// Grid: 8 col-blocks x 48 K-splits = 384 blocks. Each computes a 64x64 fp32
// partial tile over a K-chunk of 128 and writes it to part[ks]. Deterministic
// (no atomics) so the replay re-validation sees identical bits each run.

#define KSPLIT 48

__global__ __launch_bounds__(256)
void k_fc1_partial(const float* __restrict__ aggr, const float* __restrict__ W,
                   float* __restrict__ part) {
    __shared__ float As[64 * 132];
    const int t = threadIdx.x;
    const int cb = (blockIdx.x & 7) * 64;
    const int ks = blockIdx.x >> 3;
    const int kb = ks * 128;

    {
        int r = t >> 2, seg = (t & 3) * 32;
#pragma unroll
        for (int i = 0; i < 8; ++i)
            *(float4*)&As[r * 132 + seg + i * 4] =
                *(const float4*)&aggr[(size_t)r * 6144 + kb + seg + i * 4];
    }
    __syncthreads();

    const int r0 = (t >> 4) << 2;
    const int c0 = (t & 15) << 2;
    float acc[4][4];
#pragma unroll
    for (int i = 0; i < 4; ++i)
#pragma unroll
        for (int j = 0; j < 4; ++j) acc[i][j] = 0.f;

#pragma unroll 4
    for (int kk = 0; kk < 128; ++kk) {
        float4 w = *(const float4*)&W[(size_t)(kb + kk) * 512 + cb + c0];
#pragma unroll
        for (int i = 0; i < 4; ++i) {
            float a = As[(r0 + i) * 132 + kk];
            acc[i][0] += a * w.x; acc[i][1] += a * w.y;
            acc[i][2] += a * w.z; acc[i][3] += a * w.w;
        }
    }

    float* pp = part + (size_t)ks * (64 * 512);
#pragma unroll
    for (int i = 0; i < 4; ++i)
        *(float4*)&pp[(size_t)(r0 + i) * 512 + cb + c0] = *(float4*)&acc[i][0];
}

__global__ void k_fc1_reduce(const float* __restrict__ part,
                             const float* __restrict__ bias,
                             const float* __restrict__ g, const float* __restrict__ bb,
                             const float* __restrict__ m, const float* __restrict__ v,
                             float* __restrict__ h1) {
    int i = blockIdx.x * 256 + threadIdx.x;   // 64*512 = 32768 outputs
    if (i >= 64 * 512) return;
    float s = 0.f;
    for (int ks = 0; ks < KSPLIT; ++ks) s += part[ks * 32768 + i];
    int c = i & 511;
    float x = s + bias[c];
    float sl = x / (1.f + __expf(-x));                        // silu
    h1[i] = (sl - m[c]) * rsqrtf(v[c] + 1e-5f) * g[c] + bb[c];  // bn1
}

// ---------------- head: fc2+silu+bn2 -> fc3 -> softmax ----------------

__global__ __launch_bounds__(256)
void k_head(const float* __restrict__ h1,
            const float* __restrict__ fc2w, const float* __restrict__ fc2b,
            const float* __restrict__ g2, const float* __restrict__ b2,
            const float* __restrict__ m2, const float* __restrict__ v2,
            const float* __restrict__ fc3w, const float* __restrict__ fc3b,
            float* __restrict__ out) {
    __shared__ float row[512];
    __shared__ float red[8 * 32];
    __shared__ float h2[32];
    const int b = blockIdx.x, t = threadIdx.x;
    row[t] = h1[(size_t)b * 512 + t];
    row[t + 256] = h1[(size_t)b * 512 + 256 + t];
    __syncthreads();
    {
        int c = t & 31, part = t >> 5;
        float s = 0.f;
        for (int k = part * 64; k < part * 64 + 64; ++k) s += row[k] * fc2w[k * 32 + c];
        red[part * 32 + c] = s;
    }
    __syncthreads();
    if (t < 32) {
        float vv = 0.f;
        for (int p = 0; p < 8; ++p) vv += red[p * 32 + t];
        vv += fc2b[t];
        float sl = vv / (1.f + __expf(-vv));
        h2[t] = (sl - m2[t]) * rsqrtf(v2[t] + 1e-5f) * g2[t] + b2[t];
    }
    __syncthreads();
    if (t == 0) {
        float l0 = fc3b[0], l1 = fc3b[1];
        for (int k = 0; k < 32; ++k) { l0 += h2[k] * fc3w[k * 2]; l1 += h2[k] * fc3w[k * 2 + 1]; }
        float mx = fmaxf(l0, l1);
        float e0 = __expf(l0 - mx), e1 = __expf(l1 - mx);
        float inv = 1.f / (e0 + e1);
        out[b * 2] = e0 * inv;
        out[b * 2 + 1] = e1 * inv;
    }
}

// ---------------- launch ----------------

extern "C" void kernel_launch(void* const* d_in, const int* in_sizes, int n_in,
                              void* d_out, int out_size, void* d_ws, size_t ws_size,
                              hipStream_t stream) {
    (void)in_sizes; (void)n_in; (void)out_size;

    const float* x    = (const float*)d_in[0];
    const int*   ei   = (const int*)d_in[1];
    const float* pe   = (const float*)d_in[2];
    const float* W1   = (const float*)d_in[3];
    const float* b1   = (const float*)d_in[4];
    const float* W2   = (const float*)d_in[5];
    const float* b2   = (const float*)d_in[6];
    const float* fc1w = (const float*)d_in[7];
    const float* fc1b = (const float*)d_in[8];
    const float* fc2w = (const float*)d_in[9];
    const float* fc2b = (const float*)d_in[10];
    const float* fc3w = (const float*)d_in[11];
    const float* fc3b = (const float*)d_in[12];
    const float* bn1g = (const float*)d_in[13];
    const float* bn1b = (const float*)d_in[14];
    const float* bn1m = (const float*)d_in[15];
    const float* bn1v = (const float*)d_in[16];
    const float* bn2g = (const float*)d_in[17];
    const float* bn2b = (const float*)d_in[18];
    const float* bn2m = (const float*)d_in[19];
    const float* bn2v = (const float*)d_in[20];
    float* out = (float*)d_out;

    char* ws = (char*)d_ws;
    float* A1   = (float*)(ws + 0);            // N*84*4  = 21,676,032
    float* t1   = (float*)(ws + 21676032);     // N*128*4 = 33,030,144
    float* A2   = (float*)(ws + 54706176);     // 33,030,144
    float* q    = (float*)(ws + 87736320);     // 33,030,144
    float* ctx  = (float*)(ws + 120766464);    // 33,030,144
    float* aggr = (float*)(ws + 153796608);    // 64*6144*4 = 1,572,864
    float* h1   = (float*)(ws + 155369472);    // 64*512*4  = 131,072
    int*   fill = (int*)  (ws + 155500544);    // N*4 = 258,048
    int*   csr  = (int*)  (ws + 155758592);    // N*64*4 = 16,515,072
    // part aliases A1 (free after k_gemm<84>): 48*64*512*4 = 6,291,456 < 21.6MB
    float* part = A1;
    // total = 172,273,664 bytes
    if (ws_size < 172273664ull) return;

    k_zero_fill<<<(NNODE + 255) / 256, 256, 0, stream>>>(fill);
    k_scatter<<<(NEDGE + 255) / 256, 256, 0, stream>>>(ei, fill, csr);
    k_agg4<21><<<(NNODE * 21) / 256, 256, 0, stream>>>((const float4*)x, fill, csr,
                                                       (float4*)A1);
    k_gemm<84, 85, false><<<NNODE / 64, 256, 0, stream>>>(A1, W1, b1, nullptr, t1);
    k_agg4<32><<<(NNODE * 32) / 256, 256, 0, stream>>>((const float4*)t1, fill, csr,
                                                       (float4*)A2);
    k_gemm<128, 132, true><<<NNODE / 64, 256, 0, stream>>>(A2, W2, b2, pe, q);
    k_flash<<<BATCH * 16, 256, 0, stream>>>(q, ctx);
    k_pool<<<BATCH * WIN, 128, 0, stream>>>(t1, ctx, aggr);
    k_fc1_partial<<<8 * KSPLIT, 256, 0, stream>>>(aggr, fc1w, part);
    k_fc1_reduce<<<128, 256, 0, stream>>>(part, fc1b, bn1g, bn1b, bn1m, bn1v, h1);
    k_head<<<BATCH, 256, 0, stream>>>(h1, fc2w, fc2b, bn2g, bn2b, bn2m, bn2v,
                                      fc3w, fc3b, out);
}

// Round 5
// 587.863 us; speedup vs baseline: 3.3966x; 1.7210x over previous
//
#include <hip/hip_runtime.h>
#include <math.h>

#define ROI 84
#define WIN 12
#define HID 128
#define BATCH 64
#define SEQ (ROI * WIN)              // 1008
#define NNODE (BATCH * SEQ)          // 64512
#define NEDGE (NNODE * 16)           // 1032192
#define MAXDEG 64

typedef __attribute__((ext_vector_type(8))) __bf16 bf16x8;
typedef __attribute__((ext_vector_type(4))) float f32x4;
typedef __attribute__((ext_vector_type(8))) unsigned short u16x8;

__device__ inline unsigned short f2bf(float x) {
    union { float f; unsigned u; } v; v.f = x;
    unsigned r = v.u + 0x7fff + ((v.u >> 16) & 1);   // RNE
    return (unsigned short)(r >> 16);
}

// ---------------- CSR build ----------------

__global__ void k_zero_fill(int* fill) {
    int i = blockIdx.x * 256 + threadIdx.x;
    if (i < NNODE) fill[i] = 0;
}

__global__ void k_scatter(const int* __restrict__ ei, int* __restrict__ fill,
                          int* __restrict__ csr) {
    int e = blockIdx.x * 256 + threadIdx.x;
    if (e >= NEDGE) return;
    bool is64 = true;
#pragma unroll
    for (int k = 0; k < 8; ++k) is64 = is64 && (ei[2 * k + 1] == 0);
    int s, d;
    if (is64) { s = ei[2 * e]; d = ei[2 * (NEDGE + e)]; }
    else      { s = ei[e];     d = ei[NEDGE + e]; }
    if (s < 0 || s >= NNODE || d < 0 || d >= NNODE) return;
    int pos = atomicAdd(&fill[d], 1);
    if (pos < MAXDEG) csr[d * MAXDEG + pos] = s;
}

// ---------------- GIN aggregation (float4) ----------------

template <int D4>
__global__ void k_agg4(const float4* __restrict__ h, const int* __restrict__ fill,
                       const int* __restrict__ csr, float4* __restrict__ out) {
    int idx = blockIdx.x * 256 + threadIdx.x;
    if (idx >= NNODE * D4) return;
    int n = idx / D4;
    int f = idx - n * D4;
    int deg = fill[n];
    if (deg > MAXDEG) deg = MAXDEG;
    const int* lst = csr + n * MAXDEG;
    float4 s = h[(size_t)n * D4 + f];
    int j = 0;
    for (; j + 2 <= deg; j += 2) {
        float4 v0 = h[(size_t)lst[j] * D4 + f];
        float4 v1 = h[(size_t)lst[j + 1] * D4 + f];
        s.x += v0.x + v1.x; s.y += v0.y + v1.y;
        s.z += v0.z + v1.z; s.w += v0.w + v1.w;
    }
    if (j < deg) {
        float4 v0 = h[(size_t)lst[j] * D4 + f];
        s.x += v0.x; s.y += v0.y; s.z += v0.z; s.w += v0.w;
    }
    out[idx] = s;
}

// ---------------- GEMM: out[N,128] = A[N,K] @ W[K,128] + bias ----------------

template <int K, int KPAD>
__global__ __launch_bounds__(256)
void k_gemm(const float* __restrict__ A, const float* __restrict__ W,
            const float* __restrict__ bias, float* __restrict__ out) {
    __shared__ float As[64 * KPAD];
    const int t = threadIdx.x;
    const int row0 = blockIdx.x * 64;

    const int KF = K / 4;
    for (int i = t; i < 64 * KF; i += 256) {
        int r = i / KF, c4 = i - r * KF;
        *(float4*)&As[r * KPAD + c4 * 4] =
            *(const float4*)&A[(size_t)(row0 + r) * K + c4 * 4];
    }
    __syncthreads();

    const int r0 = (t >> 4) << 2;
    const int c0 = (t & 15) << 3;
    float acc[4][8];
#pragma unroll
    for (int i = 0; i < 4; ++i)
#pragma unroll
        for (int j = 0; j < 8; ++j) acc[i][j] = 0.f;

#pragma unroll 4
    for (int k = 0; k < K; ++k) {
        float4 w0 = *(const float4*)&W[k * 128 + c0];
        float4 w1 = *(const float4*)&W[k * 128 + c0 + 4];
#pragma unroll
        for (int i = 0; i < 4; ++i) {
            float a = As[(r0 + i) * KPAD + k];
            acc[i][0] += a * w0.x; acc[i][1] += a * w0.y;
            acc[i][2] += a * w0.z; acc[i][3] += a * w0.w;
            acc[i][4] += a * w1.x; acc[i][5] += a * w1.y;
            acc[i][6] += a * w1.z; acc[i][7] += a * w1.w;
        }
    }

    float4 b0 = *(const float4*)&bias[c0];
    float4 b1 = *(const float4*)&bias[c0 + 4];
#pragma unroll
    for (int i = 0; i < 4; ++i) {
        int gr = row0 + r0 + i;
        float4 o0, o1;
        o0.x = acc[i][0] + b0.x; o0.y = acc[i][1] + b0.y;
        o0.z = acc[i][2] + b0.z; o0.w = acc[i][3] + b0.w;
        o1.x = acc[i][4] + b1.x; o1.y = acc[i][5] + b1.y;
        o1.z = acc[i][6] + b1.z; o1.w = acc[i][7] + b1.w;
        *(float4*)&out[(size_t)gr * 128 + c0] = o0;
        *(float4*)&out[(size_t)gr * 128 + c0 + 4] = o1;
    }
}

// GEMM variant: adds pe and writes bf16 (flash attention input)
__global__ __launch_bounds__(256)
void k_gemm_bf16(const float* __restrict__ A, const float* __restrict__ W,
                 const float* __restrict__ bias, const float* __restrict__ pe,
                 unsigned short* __restrict__ out) {
    __shared__ float As[64 * 132];
    const int t = threadIdx.x;
    const int row0 = blockIdx.x * 64;

    for (int i = t; i < 64 * 32; i += 256) {
        int r = i / 32, c4 = i - r * 32;
        *(float4*)&As[r * 132 + c4 * 4] =
            *(const float4*)&A[(size_t)(row0 + r) * 128 + c4 * 4];
    }
    __syncthreads();

    const int r0 = (t >> 4) << 2;
    const int c0 = (t & 15) << 3;
    float acc[4][8];
#pragma unroll
    for (int i = 0; i < 4; ++i)
#pragma unroll
        for (int j = 0; j < 8; ++j) acc[i][j] = 0.f;

#pragma unroll 4
    for (int k = 0; k < 128; ++k) {
        float4 w0 = *(const float4*)&W[k * 128 + c0];
        float4 w1 = *(const float4*)&W[k * 128 + c0 + 4];
#pragma unroll
        for (int i = 0; i < 4; ++i) {
            float a = As[(r0 + i) * 132 + k];
            acc[i][0] += a * w0.x; acc[i][1] += a * w0.y;
            acc[i][2] += a * w0.z; acc[i][3] += a * w0.w;
            acc[i][4] += a * w1.x; acc[i][5] += a * w1.y;
            acc[i][6] += a * w1.z; acc[i][7] += a * w1.w;
        }
    }

    float4 b0 = *(const float4*)&bias[c0];
    float4 b1 = *(const float4*)&bias[c0 + 4];
#pragma unroll
    for (int i = 0; i < 4; ++i) {
        int gr = row0 + r0 + i;
        const float* pp = pe + (size_t)(gr % SEQ) * 128;
        float4 p0 = *(const float4*)&pp[c0];
        float4 p1 = *(const float4*)&pp[c0 + 4];
        u16x8 o;
        o[0] = f2bf(acc[i][0] + b0.x + p0.x);
        o[1] = f2bf(acc[i][1] + b0.y + p0.y);
        o[2] = f2bf(acc[i][2] + b0.z + p0.z);
        o[3] = f2bf(acc[i][3] + b0.w + p0.w);
        o[4] = f2bf(acc[i][4] + b1.x + p1.x);
        o[5] = f2bf(acc[i][5] + b1.y + p1.y);
        o[6] = f2bf(acc[i][6] + b1.z + p1.z);
        o[7] = f2bf(acc[i][7] + b1.w + p1.w);
        *(u16x8*)&out[(size_t)gr * 128 + c0] = o;
    }
}

// ---------------- MFMA flash self-attention (q = k = v) ----------------
// 1024 blocks (64 batches x 16 q-tiles of 64 rows), 256 threads (4 waves).
// Per block: loop 16 K-tiles of 64 keys (covers 1024, mask >=1008).
// Wave w owns q rows [qrow0+16w, qrow0+16w+16). Q stays in registers.
// LDS: Ks 64x128 bf16 (swz ^((key&7)<<4)); Vt 128x64 bf16
// (swz ^((d&7)<<4)^(((d>>4)&3)<<5)); P per-wave 16x64 bf16 (swz ^((row&7)<<4)).

__global__ __launch_bounds__(256, 4)
void k_flash_mfma(const unsigned short* __restrict__ qbf, float* __restrict__ ctx) {
    __shared__ unsigned short Ks[64 * 128];
    __shared__ unsigned short Vt[128 * 64];
    __shared__ unsigned short Pl[4][1024];

    const int t = threadIdx.x;
    const int lane = t & 63;
    const int w = t >> 6;
    const int r = lane & 15;
    const int h = lane >> 4;
    const int b = blockIdx.x >> 4;
    const int qrow0 = (blockIdx.x & 15) * 64;
    const unsigned short* qb = qbf + (size_t)b * SEQ * HID;
    char* Pw = (char*)&Pl[w][0];

    // Q fragments in registers (A-frag: row = lane&15, k-octet = lane>>4)
    const int qrow = qrow0 + w * 16 + r;
    const int qrc = qrow < SEQ ? qrow : SEQ - 1;
    bf16x8 Qf[4];
#pragma unroll
    for (int ds = 0; ds < 4; ++ds)
        Qf[ds] = *(const bf16x8*)&qb[(size_t)qrc * 128 + ds * 32 + h * 8];

    f32x4 O[8];
#pragma unroll
    for (int dt = 0; dt < 8; ++dt) O[dt] = (f32x4){0.f, 0.f, 0.f, 0.f};
    float m_[4], l_[4];
#pragma unroll
    for (int i = 0; i < 4; ++i) { m_[i] = -1e30f; l_[i] = 0.f; }

    const float scale = 0.08838834764831845f;  // 1/sqrt(128)

    for (int kt = 0; kt < 16; ++kt) {
        __syncthreads();
        // ---- stage K tile (row-major) + V^T tile into LDS ----
        {
            const int kp = t >> 3;             // key pair 0..31
            const int dseg = (t & 7) * 16;     // 16 d's
            const int k0 = kp * 2, k1 = k0 + 1;
            const int g0 = kt * 64 + k0;
            const u16x8 zz = {0, 0, 0, 0, 0, 0, 0, 0};
            u16x8 a0 = zz, a1 = zz, c0 = zz, c1 = zz;
            if (g0 < SEQ) {
                a0 = *(const u16x8*)&qb[(size_t)g0 * 128 + dseg];
                a1 = *(const u16x8*)&qb[(size_t)g0 * 128 + dseg + 8];
            }
            if (g0 + 1 < SEQ) {
                c0 = *(const u16x8*)&qb[(size_t)(g0 + 1) * 128 + dseg];
                c1 = *(const u16x8*)&qb[(size_t)(g0 + 1) * 128 + dseg + 8];
            }
            *(u16x8*)((char*)Ks + ((k0 * 256 + dseg * 2) ^ ((k0 & 7) << 4))) = a0;
            *(u16x8*)((char*)Ks + ((k0 * 256 + dseg * 2 + 16) ^ ((k0 & 7) << 4))) = a1;
            *(u16x8*)((char*)Ks + ((k1 * 256 + dseg * 2) ^ ((k1 & 7) << 4))) = c0;
            *(u16x8*)((char*)Ks + ((k1 * 256 + dseg * 2 + 16) ^ ((k1 & 7) << 4))) = c1;
#pragma unroll
            for (int j = 0; j < 16; ++j) {
                int d = dseg + j;
                unsigned short lo = (j < 8) ? a0[j] : a1[j - 8];
                unsigned short hi = (j < 8) ? c0[j] : c1[j - 8];
                unsigned val = (unsigned)lo | ((unsigned)hi << 16);
                *(unsigned*)((char*)Vt + ((d * 128 + k0 * 2) ^ ((d & 7) << 4)
                                          ^ (((d >> 4) & 3) << 5))) = val;
            }
        }
        __syncthreads();

        // ---- QK^T: S[kt4] = Q(16x128) . K^T, keys kt4*16+r ----
        f32x4 S[4];
#pragma unroll
        for (int kt4 = 0; kt4 < 4; ++kt4) {
            int key = kt4 * 16 + r;
            f32x4 s = (f32x4){0.f, 0.f, 0.f, 0.f};
#pragma unroll
            for (int ds = 0; ds < 4; ++ds) {
                bf16x8 kb = *(const bf16x8*)((const char*)Ks +
                    ((key * 256 + (ds * 32 + h * 8) * 2) ^ ((key & 7) << 4)));
                s = __builtin_amdgcn_mfma_f32_16x16x32_bf16(Qf[ds], kb, s, 0, 0, 0);
            }
            S[kt4] = s;
        }

        // ---- online softmax (C/D layout: col=key=r, row=h*4+i) ----
        float mx[4] = {-1e30f, -1e30f, -1e30f, -1e30f};
#pragma unroll
        for (int kt4 = 0; kt4 < 4; ++kt4) {
            bool kvalid = (kt * 64 + kt4 * 16 + r) < SEQ;
#pragma unroll
            for (int i = 0; i < 4; ++i) {
                float v = kvalid ? S[kt4][i] * scale : -1e30f;
                S[kt4][i] = v;
                mx[i] = fmaxf(mx[i], v);
            }
        }
#pragma unroll
        for (int i = 0; i < 4; ++i) {
            float v = mx[i];
            v = fmaxf(v, __shfl_xor(v, 1));
            v = fmaxf(v, __shfl_xor(v, 2));
            v = fmaxf(v, __shfl_xor(v, 4));
            v = fmaxf(v, __shfl_xor(v, 8));
            float mn = fmaxf(m_[i], v);
            mx[i] = __expf(m_[i] - mn);     // alpha
            m_[i] = mn;
        }
        float ps[4] = {0.f, 0.f, 0.f, 0.f};
#pragma unroll
        for (int kt4 = 0; kt4 < 4; ++kt4)
#pragma unroll
            for (int i = 0; i < 4; ++i) {
                float p = __expf(S[kt4][i] - m_[i]);
                ps[i] += p;
                *(unsigned short*)(Pw + (((h * 4 + i) * 128 + (kt4 * 16 + r) * 2)
                                         ^ (((h * 4 + i) & 7) << 4))) = f2bf(p);
            }
#pragma unroll
        for (int i = 0; i < 4; ++i) {
            float v = ps[i];
            v += __shfl_xor(v, 1);
            v += __shfl_xor(v, 2);
            v += __shfl_xor(v, 4);
            v += __shfl_xor(v, 8);
            l_[i] = l_[i] * mx[i] + v;
        }
#pragma unroll
        for (int dt = 0; dt < 8; ++dt)
#pragma unroll
            for (int i = 0; i < 4; ++i) O[dt][i] *= mx[i];

        // ---- PV: O += P(16x64) . V(64x128) ----
#pragma unroll
        for (int kstep = 0; kstep < 2; ++kstep) {
            bf16x8 pa = *(const bf16x8*)((const char*)Pw +
                ((r * 128 + (kstep * 32 + h * 8) * 2) ^ ((r & 7) << 4)));
#pragma unroll
            for (int dt = 0; dt < 8; ++dt) {
                int d = dt * 16 + r;
                bf16x8 vb = *(const bf16x8*)((const char*)Vt +
                    ((d * 128 + (kstep * 32 + h * 8) * 2) ^ ((d & 7) << 4)
                     ^ (((d >> 4) & 3) << 5)));
                O[dt] = __builtin_amdgcn_mfma_f32_16x16x32_bf16(pa, vb, O[dt], 0, 0, 0);
            }
        }
    }

    // ---- epilogue: O / l ----
#pragma unroll
    for (int i = 0; i < 4; ++i) {
        int qq = qrow0 + w * 16 + h * 4 + i;
        if (qq < SEQ) {
            float inv = 1.f / l_[i];
            size_t base = ((size_t)b * SEQ + qq) * 128 + r;
#pragma unroll
            for (int dt = 0; dt < 8; ++dt)
                ctx[base + dt * 16] = O[dt][i] * inv;
        }
    }
}

// ---------------- pooling ----------------

__global__ void k_pool(const float* __restrict__ t1, const float* __restrict__ ctx,
                       float* __restrict__ aggr) {
    int bw = blockIdx.x;
    int b = bw / WIN, w = bw - b * WIN;
    int c = threadIdx.x;
    const float* p1 = t1 + ((size_t)(b * SEQ + w * ROI)) * HID + c;
    const float* p2 = ctx + ((size_t)(b * SEQ + w * ROI)) * HID + c;
    float mx1 = -INFINITY, sm1 = 0.f, mx2 = -INFINITY, sm2 = 0.f;
    for (int r = 0; r < ROI; ++r) {
        float a = p1[r * HID]; mx1 = fmaxf(mx1, a); sm1 += a;
        float d = p2[r * HID]; mx2 = fmaxf(mx2, d); sm2 += d;
    }
    float* o = aggr + (size_t)b * 6144 + w * 512;
    o[c] = mx1;
    o[128 + c] = sm1 * (1.f / 84.f);
    o[256 + c] = mx2;
    o[384 + c] = sm2 * (1.f / 84.f);
}

// ---------------- fc1 split-K ----------------

#define KSPLIT 48

__global__ __launch_bounds__(256)
void k_fc1_partial(const float* __restrict__ aggr, const float* __restrict__ W,
                   float* __restrict__ part) {
    __shared__ float As[64 * 132];
    const int t = threadIdx.x;
    const int cb = (blockIdx.x & 7) * 64;
    const int ks = blockIdx.x >> 3;
    const int kb = ks * 128;

    {
        int r = t >> 2, seg = (t & 3) * 32;
#pragma unroll
        for (int i = 0; i < 8; ++i)
            *(float4*)&As[r * 132 + seg + i * 4] =
                *(const float4*)&aggr[(size_t)r * 6144 + kb + seg + i * 4];
    }
    __syncthreads();

    const int r0 = (t >> 4) << 2;
    const int c0 = (t & 15) << 2;
    float acc[4][4];
#pragma unroll
    for (int i = 0; i < 4; ++i)
#pragma unroll
        for (int j = 0; j < 4; ++j) acc[i][j] = 0.f;

#pragma unroll 4
    for (int kk = 0; kk < 128; ++kk) {
        float4 w = *(const float4*)&W[(size_t)(kb + kk) * 512 + cb + c0];
#pragma unroll
        for (int i = 0; i < 4; ++i) {
            float a = As[(r0 + i) * 132 + kk];
            acc[i][0] += a * w.x; acc[i][1] += a * w.y;
            acc[i][2] += a * w.z; acc[i][3] += a * w.w;
        }
    }

    float* pp = part + (size_t)ks * (64 * 512);
#pragma unroll
    for (int i = 0; i < 4; ++i)
        *(float4*)&pp[(size_t)(r0 + i) * 512 + cb + c0] = *(float4*)&acc[i][0];
}

__global__ void k_fc1_reduce(const float* __restrict__ part,
                             const float* __restrict__ bias,
                             const float* __restrict__ g, const float* __restrict__ bb,
                             const float* __restrict__ m, const float* __restrict__ v,
                             float* __restrict__ h1) {
    int i = blockIdx.x * 256 + threadIdx.x;
    if (i >= 64 * 512) return;
    float s = 0.f;
    for (int ks = 0; ks < KSPLIT; ++ks) s += part[ks * 32768 + i];
    int c = i & 511;
    float x = s + bias[c];
    float sl = x / (1.f + __expf(-x));
    h1[i] = (sl - m[c]) * rsqrtf(v[c] + 1e-5f) * g[c] + bb[c];
}

// ---------------- head ----------------

__global__ __launch_bounds__(256)
void k_head(const float* __restrict__ h1,
            const float* __restrict__ fc2w, const float* __restrict__ fc2b,
            const float* __restrict__ g2, const float* __restrict__ b2,
            const float* __restrict__ m2, const float* __restrict__ v2,
            const float* __restrict__ fc3w, const float* __restrict__ fc3b,
            float* __restrict__ out) {
    __shared__ float row[512];
    __shared__ float red[8 * 32];
    __shared__ float h2[32];
    const int b = blockIdx.x, t = threadIdx.x;
    row[t] = h1[(size_t)b * 512 + t];
    row[t + 256] = h1[(size_t)b * 512 + 256 + t];
    __syncthreads();
    {
        int c = t & 31, part = t >> 5;
        float s = 0.f;
        for (int k = part * 64; k < part * 64 + 64; ++k) s += row[k] * fc2w[k * 32 + c];
        red[part * 32 + c] = s;
    }
    __syncthreads();
    if (t < 32) {
        float vv = 0.f;
        for (int p = 0; p < 8; ++p) vv += red[p * 32 + t];
        vv += fc2b[t];
        float sl = vv / (1.f + __expf(-vv));
        h2[t] = (sl - m2[t]) * rsqrtf(v2[t] + 1e-5f) * g2[t] + b2[t];
    }
    __syncthreads();
    if (t == 0) {
        float l0 = fc3b[0], l1 = fc3b[1];
        for (int k = 0; k < 32; ++k) { l0 += h2[k] * fc3w[k * 2]; l1 += h2[k] * fc3w[k * 2 + 1]; }
        float mx = fmaxf(l0, l1);
        float e0 = __expf(l0 - mx), e1 = __expf(l1 - mx);
        float inv = 1.f / (e0 + e1);
        out[b * 2] = e0 * inv;
        out[b * 2 + 1] = e1 * inv;
    }
}

// ---------------- launch ----------------

extern "C" void kernel_launch(void* const* d_in, const int* in_sizes, int n_in,
                              void* d_out, int out_size, void* d_ws, size_t ws_size,
                              hipStream_t stream) {
    (void)in_sizes; (void)n_in; (void)out_size;

    const float* x    = (const float*)d_in[0];
    const int*   ei   = (const int*)d_in[1];
    const float* pe   = (const float*)d_in[2];
    const float* W1   = (const float*)d_in[3];
    const float* b1   = (const float*)d_in[4];
    const float* W2   = (const float*)d_in[5];
    const float* b2   = (const float*)d_in[6];
    const float* fc1w = (const float*)d_in[7];
    const float* fc1b = (const float*)d_in[8];
    const float* fc2w = (const float*)d_in[9];
    const float* fc2b = (const float*)d_in[10];
    const float* fc3w = (const float*)d_in[11];
    const float* fc3b = (const float*)d_in[12];
    const float* bn1g = (const float*)d_in[13];
    const float* bn1b = (const float*)d_in[14];
    const float* bn1m = (const float*)d_in[15];
    const float* bn1v = (const float*)d_in[16];
    const float* bn2g = (const float*)d_in[17];
    const float* bn2b = (const float*)d_in[18];
    const float* bn2m = (const float*)d_in[19];
    const float* bn2v = (const float*)d_in[20];
    float* out = (float*)d_out;

    char* ws = (char*)d_ws;
    float*          A1   = (float*)(ws + 0);            // 21,676,032
    float*          t1   = (float*)(ws + 21676032);     // 33,030,144
    float*          A2   = (float*)(ws + 54706176);     // 33,030,144
    unsigned short* qbf  = (unsigned short*)(ws + 87736320);  // N*128*2 = 16,515,072
    float*          ctx  = (float*)(ws + 120766464);    // 33,030,144
    float*          aggr = (float*)(ws + 153796608);    // 1,572,864
    float*          h1   = (float*)(ws + 155369472);    // 131,072
    int*            fill = (int*)  (ws + 155500544);    // 258,048
    int*            csr  = (int*)  (ws + 155758592);    // 16,515,072
    float*          part = A1;                          // fc1 partials alias A1
    if (ws_size < 172273664ull) return;

    k_zero_fill<<<(NNODE + 255) / 256, 256, 0, stream>>>(fill);
    k_scatter<<<(NEDGE + 255) / 256, 256, 0, stream>>>(ei, fill, csr);
    k_agg4<21><<<(NNODE * 21) / 256, 256, 0, stream>>>((const float4*)x, fill, csr,
                                                       (float4*)A1);
    k_gemm<84, 85><<<NNODE / 64, 256, 0, stream>>>(A1, W1, b1, t1);
    k_agg4<32><<<(NNODE * 32) / 256, 256, 0, stream>>>((const float4*)t1, fill, csr,
                                                       (float4*)A2);
    k_gemm_bf16<<<NNODE / 64, 256, 0, stream>>>(A2, W2, b2, pe, qbf);
    k_flash_mfma<<<BATCH * 16, 256, 0, stream>>>(qbf, ctx);
    k_pool<<<BATCH * WIN, 128, 0, stream>>>(t1, ctx, aggr);
    k_fc1_partial<<<8 * KSPLIT, 256, 0, stream>>>(aggr, fc1w, part);
    k_fc1_reduce<<<128, 256, 0, stream>>>(part, fc1b, bn1g, bn1b, bn1m, bn1v, h1);
    k_head<<<BATCH, 256, 0, stream>>>(h1, fc2w, fc2b, bn2g, bn2b, bn2m, bn2v,
                                      fc3w, fc3b, out);
}

// Round 7
// 521.952 us; speedup vs baseline: 3.8255x; 1.1263x over previous
//
#include <hip/hip_runtime.h>
#include <math.h>

#define ROI 84
#define WIN 12
#define HID 128
#define BATCH 64
#define SEQ (ROI * WIN)              // 1008
#define NNODE (BATCH * SEQ)          // 64512
#define NEDGE (NNODE * 16)           // 1032192
#define MAXDEG 64

typedef __attribute__((ext_vector_type(8))) __bf16 bf16x8;
typedef __attribute__((ext_vector_type(4))) float f32x4;
typedef __attribute__((ext_vector_type(8))) unsigned short u16x8;

__device__ inline unsigned short f2bf(float x) {
    union { float f; unsigned u; } v; v.f = x;
    unsigned r = v.u + 0x7fff + ((v.u >> 16) & 1);   // RNE
    return (unsigned short)(r >> 16);
}

// ---------------- CSR build ----------------

__global__ void k_zero_fill(int* fill) {
    int i = blockIdx.x * 256 + threadIdx.x;
    if (i < NNODE) fill[i] = 0;
}

__global__ void k_scatter(const int* __restrict__ ei, int* __restrict__ fill,
                          int* __restrict__ csr) {
    int e = blockIdx.x * 256 + threadIdx.x;
    if (e >= NEDGE) return;
    bool is64 = true;
#pragma unroll
    for (int k = 0; k < 8; ++k) is64 = is64 && (ei[2 * k + 1] == 0);
    int s, d;
    if (is64) { s = ei[2 * e]; d = ei[2 * (NEDGE + e)]; }
    else      { s = ei[e];     d = ei[NEDGE + e]; }
    if (s < 0 || s >= NNODE || d < 0 || d >= NNODE) return;
    int pos = atomicAdd(&fill[d], 1);
    if (pos < MAXDEG) csr[d * MAXDEG + pos] = s;
}

// ---------------- GIN aggregation (float4) ----------------

template <int D4>
__global__ void k_agg4(const float4* __restrict__ h, const int* __restrict__ fill,
                       const int* __restrict__ csr, float4* __restrict__ out) {
    int idx = blockIdx.x * 256 + threadIdx.x;
    if (idx >= NNODE * D4) return;
    int n = idx / D4;
    int f = idx - n * D4;
    int deg = fill[n];
    if (deg > MAXDEG) deg = MAXDEG;
    const int* lst = csr + n * MAXDEG;
    float4 s = h[(size_t)n * D4 + f];
    int j = 0;
    for (; j + 2 <= deg; j += 2) {
        float4 v0 = h[(size_t)lst[j] * D4 + f];
        float4 v1 = h[(size_t)lst[j + 1] * D4 + f];
        s.x += v0.x + v1.x; s.y += v0.y + v1.y;
        s.z += v0.z + v1.z; s.w += v0.w + v1.w;
    }
    if (j < deg) {
        float4 v0 = h[(size_t)lst[j] * D4 + f];
        s.x += v0.x; s.y += v0.y; s.z += v0.z; s.w += v0.w;
    }
    out[idx] = s;
}

// ---------------- GEMM: out[N,128] = A[N,K] @ W[K,128] + bias ----------------

template <int K, int KPAD>
__global__ __launch_bounds__(256)
void k_gemm(const float* __restrict__ A, const float* __restrict__ W,
            const float* __restrict__ bias, float* __restrict__ out) {
    __shared__ float As[64 * KPAD];
    const int t = threadIdx.x;
    const int row0 = blockIdx.x * 64;

    const int KF = K / 4;
    for (int i = t; i < 64 * KF; i += 256) {
        int r = i / KF, c4 = i - r * KF;
        *(float4*)&As[r * KPAD + c4 * 4] =
            *(const float4*)&A[(size_t)(row0 + r) * K + c4 * 4];
    }
    __syncthreads();

    const int r0 = (t >> 4) << 2;
    const int c0 = (t & 15) << 3;
    float acc[4][8];
#pragma unroll
    for (int i = 0; i < 4; ++i)
#pragma unroll
        for (int j = 0; j < 8; ++j) acc[i][j] = 0.f;

#pragma unroll 4
    for (int k = 0; k < K; ++k) {
        float4 w0 = *(const float4*)&W[k * 128 + c0];
        float4 w1 = *(const float4*)&W[k * 128 + c0 + 4];
#pragma unroll
        for (int i = 0; i < 4; ++i) {
            float a = As[(r0 + i) * KPAD + k];
            acc[i][0] += a * w0.x; acc[i][1] += a * w0.y;
            acc[i][2] += a * w0.z; acc[i][3] += a * w0.w;
            acc[i][4] += a * w1.x; acc[i][5] += a * w1.y;
            acc[i][6] += a * w1.z; acc[i][7] += a * w1.w;
        }
    }

    float4 b0 = *(const float4*)&bias[c0];
    float4 b1 = *(const float4*)&bias[c0 + 4];
#pragma unroll
    for (int i = 0; i < 4; ++i) {
        int gr = row0 + r0 + i;
        float4 o0, o1;
        o0.x = acc[i][0] + b0.x; o0.y = acc[i][1] + b0.y;
        o0.z = acc[i][2] + b0.z; o0.w = acc[i][3] + b0.w;
        o1.x = acc[i][4] + b1.x; o1.y = acc[i][5] + b1.y;
        o1.z = acc[i][6] + b1.z; o1.w = acc[i][7] + b1.w;
        *(float4*)&out[(size_t)gr * 128 + c0] = o0;
        *(float4*)&out[(size_t)gr * 128 + c0 + 4] = o1;
    }
}

// GEMM variant: adds pe and writes bf16 (flash attention input)
__global__ __launch_bounds__(256)
void k_gemm_bf16(const float* __restrict__ A, const float* __restrict__ W,
                 const float* __restrict__ bias, const float* __restrict__ pe,
                 unsigned short* __restrict__ out) {
    __shared__ float As[64 * 132];
    const int t = threadIdx.x;
    const int row0 = blockIdx.x * 64;

    for (int i = t; i < 64 * 32; i += 256) {
        int r = i / 32, c4 = i - r * 32;
        *(float4*)&As[r * 132 + c4 * 4] =
            *(const float4*)&A[(size_t)(row0 + r) * 128 + c4 * 4];
    }
    __syncthreads();

    const int r0 = (t >> 4) << 2;
    const int c0 = (t & 15) << 3;
    float acc[4][8];
#pragma unroll
    for (int i = 0; i < 4; ++i)
#pragma unroll
        for (int j = 0; j < 8; ++j) acc[i][j] = 0.f;

#pragma unroll 4
    for (int k = 0; k < 128; ++k) {
        float4 w0 = *(const float4*)&W[k * 128 + c0];
        float4 w1 = *(const float4*)&W[k * 128 + c0 + 4];
#pragma unroll
        for (int i = 0; i < 4; ++i) {
            float a = As[(r0 + i) * 132 + k];
            acc[i][0] += a * w0.x; acc[i][1] += a * w0.y;
            acc[i][2] += a * w0.z; acc[i][3] += a * w0.w;
            acc[i][4] += a * w1.x; acc[i][5] += a * w1.y;
            acc[i][6] += a * w1.z; acc[i][7] += a * w1.w;
        }
    }

    float4 b0 = *(const float4*)&bias[c0];
    float4 b1 = *(const float4*)&bias[c0 + 4];
#pragma unroll
    for (int i = 0; i < 4; ++i) {
        int gr = row0 + r0 + i;
        const float* pp = pe + (size_t)(gr % SEQ) * 128;
        float4 p0 = *(const float4*)&pp[c0];
        float4 p1 = *(const float4*)&pp[c0 + 4];
        u16x8 o;
        o[0] = f2bf(acc[i][0] + b0.x + p0.x);
        o[1] = f2bf(acc[i][1] + b0.y + p0.y);
        o[2] = f2bf(acc[i][2] + b0.z + p0.z);
        o[3] = f2bf(acc[i][3] + b0.w + p0.w);
        o[4] = f2bf(acc[i][4] + b1.x + p1.x);
        o[5] = f2bf(acc[i][5] + b1.y + p1.y);
        o[6] = f2bf(acc[i][6] + b1.z + p1.z);
        o[7] = f2bf(acc[i][7] + b1.w + p1.w);
        *(u16x8*)&out[(size_t)gr * 128 + c0] = o;
    }
}

// ---------------- MFMA flash self-attention (q = k = v) ----------------
// 512 blocks (64 batches x 8 q-tiles of 128 rows), 256 threads (4 waves).
// Wave w owns q rows [qrow0+32w, +32) as two 16-row fragments (qa=0,1).
// 16 K-tiles of 64 keys. K-tile staged via register prefetch (next tile's
// global loads issued before compute so latency hides under QK/PV).
// XCD swizzle: all 8 q-tile blocks of batch b land on XCD b%8 so the
// batch K/V (258KB) stays L2-resident (8 batches x 258KB = 2MB < 4MB).
// LDS 48KB: Ks 64x128 bf16 (swz ^((key&7)<<4)); Vt 128x64 bf16
// (swz ^((d&7)<<4)^(((d>>4)&3)<<5)); P[wave][qa] 16x64 bf16 (swz ^((row&7)<<4)).

struct Stg { u16x8 a0, a1, c0, c1; };

__device__ inline Stg load_stage(const unsigned short* qb, int kt, int t) {
    const int kp = t >> 3;
    const int dseg = (t & 7) * 16;
    const int g0 = kt * 64 + kp * 2;
    const u16x8 zz = {0, 0, 0, 0, 0, 0, 0, 0};
    Stg s; s.a0 = zz; s.a1 = zz; s.c0 = zz; s.c1 = zz;
    if (g0 < SEQ) {
        s.a0 = *(const u16x8*)&qb[(size_t)g0 * 128 + dseg];
        s.a1 = *(const u16x8*)&qb[(size_t)g0 * 128 + dseg + 8];
    }
    if (g0 + 1 < SEQ) {
        s.c0 = *(const u16x8*)&qb[(size_t)(g0 + 1) * 128 + dseg];
        s.c1 = *(const u16x8*)&qb[(size_t)(g0 + 1) * 128 + dseg + 8];
    }
    return s;
}

__device__ inline void write_stage(unsigned short* Ks, unsigned short* Vt,
                                   const Stg& s, int t) {
    const int kp = t >> 3;
    const int dseg = (t & 7) * 16;
    const int k0 = kp * 2, k1 = k0 + 1;
    *(u16x8*)((char*)Ks + ((k0 * 256 + dseg * 2) ^ ((k0 & 7) << 4))) = s.a0;
    *(u16x8*)((char*)Ks + ((k0 * 256 + dseg * 2 + 16) ^ ((k0 & 7) << 4))) = s.a1;
    *(u16x8*)((char*)Ks + ((k1 * 256 + dseg * 2) ^ ((k1 & 7) << 4))) = s.c0;
    *(u16x8*)((char*)Ks + ((k1 * 256 + dseg * 2 + 16) ^ ((k1 & 7) << 4))) = s.c1;
#pragma unroll
    for (int j = 0; j < 16; ++j) {
        int d = dseg + j;
        unsigned short lo = (j < 8) ? s.a0[j] : s.a1[j - 8];
        unsigned short hi = (j < 8) ? s.c0[j] : s.c1[j - 8];
        unsigned val = (unsigned)lo | ((unsigned)hi << 16);
        *(unsigned*)((char*)Vt + ((d * 128 + k0 * 2) ^ ((d & 7) << 4)
                                  ^ (((d >> 4) & 3) << 5))) = val;
    }
}

__global__ __launch_bounds__(256, 2)
void k_flash_mfma(const unsigned short* __restrict__ qbf, float* __restrict__ ctx) {
    __shared__ unsigned short Ks[64 * 128];
    __shared__ unsigned short Vt[128 * 64];
    __shared__ unsigned short Pl[4][2][1024];

    const int t = threadIdx.x;
    const int lane = t & 63;
    const int w = t >> 6;
    const int r = lane & 15;
    const int h = lane >> 4;
    // XCD swizzle: p%8 selects XCD (round-robin dispatch); put batch b on XCD b%8.
    const int p = blockIdx.x;
    const int grp = p >> 3;
    const int b = (grp >> 3) * 8 + (p & 7);
    const int qrow0 = (grp & 7) * 128;
    const unsigned short* qb = qbf + (size_t)b * SEQ * HID;

    // Q fragments in registers, 2 sub-tiles per wave
    bf16x8 Qf[2][4];
#pragma unroll
    for (int qa = 0; qa < 2; ++qa) {
        int qrow = qrow0 + w * 32 + qa * 16 + r;
        int qrc = qrow < SEQ ? qrow : SEQ - 1;
#pragma unroll
        for (int ds = 0; ds < 4; ++ds)
            Qf[qa][ds] = *(const bf16x8*)&qb[(size_t)qrc * 128 + ds * 32 + h * 8];
    }

    f32x4 O[2][8];
#pragma unroll
    for (int qa = 0; qa < 2; ++qa)
#pragma unroll
        for (int dt = 0; dt < 8; ++dt) O[qa][dt] = (f32x4){0.f, 0.f, 0.f, 0.f};
    float m_[2][4], l_[2][4];
#pragma unroll
    for (int qa = 0; qa < 2; ++qa)
#pragma unroll
        for (int i = 0; i < 4; ++i) { m_[qa][i] = -1e30f; l_[qa][i] = 0.f; }

    const float scale = 0.08838834764831845f;  // 1/sqrt(128)

    Stg cur = load_stage(qb, 0, t);

    for (int kt = 0; kt < 16; ++kt) {
        __syncthreads();                 // previous iteration's LDS readers done
        write_stage(Ks, Vt, cur, t);
        if (kt < 15) cur = load_stage(qb, kt + 1, t);   // prefetch next tile
        __syncthreads();                 // LDS tile ready

        // ---- QK^T for both q sub-tiles (kb shared) ----
        f32x4 S[2][4];
#pragma unroll
        for (int kt4 = 0; kt4 < 4; ++kt4) {
            int key = kt4 * 16 + r;
            f32x4 s0 = (f32x4){0.f, 0.f, 0.f, 0.f};
            f32x4 s1 = (f32x4){0.f, 0.f, 0.f, 0.f};
#pragma unroll
            for (int ds = 0; ds < 4; ++ds) {
                bf16x8 kb = *(const bf16x8*)((const char*)Ks +
                    ((key * 256 + (ds * 32 + h * 8) * 2) ^ ((key & 7) << 4)));
                s0 = __builtin_amdgcn_mfma_f32_16x16x32_bf16(Qf[0][ds], kb, s0, 0, 0, 0);
                s1 = __builtin_amdgcn_mfma_f32_16x16x32_bf16(Qf[1][ds], kb, s1, 0, 0, 0);
            }
            S[0][kt4] = s0; S[1][kt4] = s1;
        }

        // ---- online softmax per sub-tile (C/D: col=key=r, row=h*4+i) ----
#pragma unroll
        for (int qa = 0; qa < 2; ++qa) {
            char* Pw = (char*)&Pl[w][qa][0];
            float mx[4] = {-1e30f, -1e30f, -1e30f, -1e30f};
#pragma unroll
            for (int kt4 = 0; kt4 < 4; ++kt4) {
                bool kvalid = (kt * 64 + kt4 * 16 + r) < SEQ;
#pragma unroll
                for (int i = 0; i < 4; ++i) {
                    float v = kvalid ? S[qa][kt4][i] * scale : -1e30f;
                    S[qa][kt4][i] = v;
                    mx[i] = fmaxf(mx[i], v);
                }
            }
#pragma unroll
            for (int i = 0; i < 4; ++i) {
                float v = mx[i];
                v = fmaxf(v, __shfl_xor(v, 1));
                v = fmaxf(v, __shfl_xor(v, 2));
                v = fmaxf(v, __shfl_xor(v, 4));
                v = fmaxf(v, __shfl_xor(v, 8));
                float mn = fmaxf(m_[qa][i], v);
                mx[i] = __expf(m_[qa][i] - mn);     // alpha
                m_[qa][i] = mn;
            }
            float ps[4] = {0.f, 0.f, 0.f, 0.f};
#pragma unroll
            for (int kt4 = 0; kt4 < 4; ++kt4)
#pragma unroll
                for (int i = 0; i < 4; ++i) {
                    float pv = __expf(S[qa][kt4][i] - m_[qa][i]);
                    ps[i] += pv;
                    *(unsigned short*)(Pw + (((h * 4 + i) * 128 + (kt4 * 16 + r) * 2)
                                             ^ (((h * 4 + i) & 7) << 4))) = f2bf(pv);
                }
#pragma unroll
            for (int i = 0; i < 4; ++i) {
                float v = ps[i];
                v += __shfl_xor(v, 1);
                v += __shfl_xor(v, 2);
                v += __shfl_xor(v, 4);
                v += __shfl_xor(v, 8);
                l_[qa][i] = l_[qa][i] * mx[i] + v;
            }
#pragma unroll
            for (int dt = 0; dt < 8; ++dt)
#pragma unroll
                for (int i = 0; i < 4; ++i) O[qa][dt][i] *= mx[i];
        }

        // ---- PV: O += P(16x64) . V(64x128), vb shared across qa ----
#pragma unroll
        for (int kstep = 0; kstep < 2; ++kstep) {
            bf16x8 pa0 = *(const bf16x8*)((const char*)&Pl[w][0][0] +
                ((r * 128 + (kstep * 32 + h * 8) * 2) ^ ((r & 7) << 4)));
            bf16x8 pa1 = *(const bf16x8*)((const char*)&Pl[w][1][0] +
                ((r * 128 + (kstep * 32 + h * 8) * 2) ^ ((r & 7) << 4)));
#pragma unroll
            for (int dt = 0; dt < 8; ++dt) {
                int d = dt * 16 + r;
                bf16x8 vb = *(const bf16x8*)((const char*)Vt +
                    ((d * 128 + (kstep * 32 + h * 8) * 2) ^ ((d & 7) << 4)
                     ^ (((d >> 4) & 3) << 5)));
                O[0][dt] = __builtin_amdgcn_mfma_f32_16x16x32_bf16(pa0, vb, O[0][dt], 0, 0, 0);
                O[1][dt] = __builtin_amdgcn_mfma_f32_16x16x32_bf16(pa1, vb, O[1][dt], 0, 0, 0);
            }
        }
    }

    // ---- epilogue: O / l ----
#pragma unroll
    for (int qa = 0; qa < 2; ++qa)
#pragma unroll
        for (int i = 0; i < 4; ++i) {
            int qq = qrow0 + w * 32 + qa * 16 + h * 4 + i;
            if (qq < SEQ) {
                float inv = 1.f / l_[qa][i];
                size_t base = ((size_t)b * SEQ + qq) * 128 + r;
#pragma unroll
                for (int dt = 0; dt < 8; ++dt)
                    ctx[base + dt * 16] = O[qa][dt][i] * inv;
            }
        }
}

// ---------------- pooling ----------------

__global__ void k_pool(const float* __restrict__ t1, const float* __restrict__ ctx,
                       float* __restrict__ aggr) {
    int bw = blockIdx.x;
    int b = bw / WIN, w = bw - b * WIN;
    int c = threadIdx.x;
    const float* p1 = t1 + ((size_t)(b * SEQ + w * ROI)) * HID + c;
    const float* p2 = ctx + ((size_t)(b * SEQ + w * ROI)) * HID + c;
    float mx1 = -INFINITY, sm1 = 0.f, mx2 = -INFINITY, sm2 = 0.f;
    for (int r = 0; r < ROI; ++r) {
        float a = p1[r * HID]; mx1 = fmaxf(mx1, a); sm1 += a;
        float d = p2[r * HID]; mx2 = fmaxf(mx2, d); sm2 += d;
    }
    float* o = aggr + (size_t)b * 6144 + w * 512;
    o[c] = mx1;
    o[128 + c] = sm1 * (1.f / 84.f);
    o[256 + c] = mx2;
    o[384 + c] = sm2 * (1.f / 84.f);
}

// ---------------- fc1 split-K ----------------

#define KSPLIT 48

__global__ __launch_bounds__(256)
void k_fc1_partial(const float* __restrict__ aggr, const float* __restrict__ W,
                   float* __restrict__ part) {
    __shared__ float As[64 * 132];
    const int t = threadIdx.x;
    const int cb = (blockIdx.x & 7) * 64;
    const int ks = blockIdx.x >> 3;
    const int kb = ks * 128;

    {
        int r = t >> 2, seg = (t & 3) * 32;
#pragma unroll
        for (int i = 0; i < 8; ++i)
            *(float4*)&As[r * 132 + seg + i * 4] =
                *(const float4*)&aggr[(size_t)r * 6144 + kb + seg + i * 4];
    }
    __syncthreads();

    const int r0 = (t >> 4) << 2;
    const int c0 = (t & 15) << 2;
    float acc[4][4];
#pragma unroll
    for (int i = 0; i < 4; ++i)
#pragma unroll
        for (int j = 0; j < 4; ++j) acc[i][j] = 0.f;

#pragma unroll 4
    for (int kk = 0; kk < 128; ++kk) {
        float4 w = *(const float4*)&W[(size_t)(kb + kk) * 512 + cb + c0];
#pragma unroll
        for (int i = 0; i < 4; ++i) {
            float a = As[(r0 + i) * 132 + kk];
            acc[i][0] += a * w.x; acc[i][1] += a * w.y;
            acc[i][2] += a * w.z; acc[i][3] += a * w.w;
        }
    }

    float* pp = part + (size_t)ks * (64 * 512);
#pragma unroll
    for (int i = 0; i < 4; ++i)
        *(float4*)&pp[(size_t)(r0 + i) * 512 + cb + c0] = *(float4*)&acc[i][0];
}

__global__ void k_fc1_reduce(const float* __restrict__ part,
                             const float* __restrict__ bias,
                             const float* __restrict__ g, const float* __restrict__ bb,
                             const float* __restrict__ m, const float* __restrict__ v,
                             float* __restrict__ h1) {
    int i = blockIdx.x * 256 + threadIdx.x;
    if (i >= 64 * 512) return;
    float s = 0.f;
    for (int ks = 0; ks < KSPLIT; ++ks) s += part[ks * 32768 + i];
    int c = i & 511;
    float x = s + bias[c];
    float sl = x / (1.f + __expf(-x));
    h1[i] = (sl - m[c]) * rsqrtf(v[c] + 1e-5f) * g[c] + bb[c];
}

// ---------------- head ----------------

__global__ __launch_bounds__(256)
void k_head(const float* __restrict__ h1,
            const float* __restrict__ fc2w, const float* __restrict__ fc2b,
            const float* __restrict__ g2, const float* __restrict__ b2,
            const float* __restrict__ m2, const float* __restrict__ v2,
            const float* __restrict__ fc3w, const float* __restrict__ fc3b,
            float* __restrict__ out) {
    __shared__ float row[512];
    __shared__ float red[8 * 32];
    __shared__ float h2[32];
    const int b = blockIdx.x, t = threadIdx.x;
    row[t] = h1[(size_t)b * 512 + t];
    row[t + 256] = h1[(size_t)b * 512 + 256 + t];
    __syncthreads();
    {
        int c = t & 31, part = t >> 5;
        float s = 0.f;
        for (int k = part * 64; k < part * 64 + 64; ++k) s += row[k] * fc2w[k * 32 + c];
        red[part * 32 + c] = s;
    }
    __syncthreads();
    if (t < 32) {
        float vv = 0.f;
        for (int p = 0; p < 8; ++p) vv += red[p * 32 + t];
        vv += fc2b[t];
        float sl = vv / (1.f + __expf(-vv));
        h2[t] = (sl - m2[t]) * rsqrtf(v2[t] + 1e-5f) * g2[t] + b2[t];
    }
    __syncthreads();
    if (t == 0) {
        float l0 = fc3b[0], l1 = fc3b[1];
        for (int k = 0; k < 32; ++k) { l0 += h2[k] * fc3w[k * 2]; l1 += h2[k] * fc3w[k * 2 + 1]; }
        float mx = fmaxf(l0, l1);
        float e0 = __expf(l0 - mx), e1 = __expf(l1 - mx);
        float inv = 1.f / (e0 + e1);
        out[b * 2] = e0 * inv;
        out[b * 2 + 1] = e1 * inv;
    }
}

// ---------------- launch ----------------

extern "C" void kernel_launch(void* const* d_in, const int* in_sizes, int n_in,
                              void* d_out, int out_size, void* d_ws, size_t ws_size,
                              hipStream_t stream) {
    (void)in_sizes; (void)n_in; (void)out_size;

    const float* x    = (const float*)d_in[0];
    const int*   ei   = (const int*)d_in[1];
    const float* pe   = (const float*)d_in[2];
    const float* W1   = (const float*)d_in[3];
    const float* b1   = (const float*)d_in[4];
    const float* W2   = (const float*)d_in[5];
    const float* b2   = (const float*)d_in[6];
    const float* fc1w = (const float*)d_in[7];
    const float* fc1b = (const float*)d_in[8];
    const float* fc2w = (const float*)d_in[9];
    const float* fc2b = (const float*)d_in[10];
    const float* fc3w = (const float*)d_in[11];
    const float* fc3b = (const float*)d_in[12];
    const float* bn1g = (const float*)d_in[13];
    const float* bn1b = (const float*)d_in[14];
    const float* bn1m = (const float*)d_in[15];
    const float* bn1v = (const float*)d_in[16];
    const float* bn2g = (const float*)d_in[17];
    const float* bn2b = (const float*)d_in[18];
    const float* bn2m = (const float*)d_in[19];
    const float* bn2v = (const float*)d_in[20];
    float* out = (float*)d_out;

    char* ws = (char*)d_ws;
    float*          A1   = (float*)(ws + 0);            // 21,676,032
    float*          t1   = (float*)(ws + 21676032);     // 33,030,144
    float*          A2   = (float*)(ws + 54706176);     // 33,030,144
    unsigned short* qbf  = (unsigned short*)(ws + 87736320);  // N*128*2 = 16,515,072
    float*          ctx  = (float*)(ws + 120766464);    // 33,030,144
    float*          aggr = (float*)(ws + 153796608);    // 1,572,864
    float*          h1   = (float*)(ws + 155369472);    // 131,072
    int*            fill = (int*)  (ws + 155500544);    // 258,048
    int*            csr  = (int*)  (ws + 155758592);    // 16,515,072
    float*          part = A1;                          // fc1 partials alias A1
    if (ws_size < 172273664ull) return;

    k_zero_fill<<<(NNODE + 255) / 256, 256, 0, stream>>>(fill);
    k_scatter<<<(NEDGE + 255) / 256, 256, 0, stream>>>(ei, fill, csr);
    k_agg4<21><<<(NNODE * 21) / 256, 256, 0, stream>>>((const float4*)x, fill, csr,
                                                       (float4*)A1);
    k_gemm<84, 85><<<NNODE / 64, 256, 0, stream>>>(A1, W1, b1, t1);
    k_agg4<32><<<(NNODE * 32) / 256, 256, 0, stream>>>((const float4*)t1, fill, csr,
                                                       (float4*)A2);
    k_gemm_bf16<<<NNODE / 64, 256, 0, stream>>>(A2, W2, b2, pe, qbf);
    k_flash_mfma<<<BATCH * 8, 256, 0, stream>>>(qbf, ctx);
    k_pool<<<BATCH * WIN, 128, 0, stream>>>(t1, ctx, aggr);
    k_fc1_partial<<<8 * KSPLIT, 256, 0, stream>>>(aggr, fc1w, part);
    k_fc1_reduce<<<128, 256, 0, stream>>>(part, fc1b, bn1g, bn1b, bn1m, bn1v, h1);
    k_head<<<BATCH, 256, 0, stream>>>(h1, fc2w, fc2b, bn2g, bn2b, bn2m, bn2v,
                                      fc3w, fc3b, out);
}

// Round 8
// 423.309 us; speedup vs baseline: 4.7170x; 1.2330x over previous
//
#include <hip/hip_runtime.h>
#include <math.h>

#define ROI 84
#define WIN 12
#define HID 128
#define BATCH 64
#define SEQ (ROI * WIN)              // 1008
#define NNODE (BATCH * SEQ)          // 64512
#define NEDGE (NNODE * 16)           // 1032192
#define MAXDEG 64

typedef __attribute__((ext_vector_type(8))) __bf16 bf16x8;
typedef __attribute__((ext_vector_type(4))) float f32x4;
typedef __attribute__((ext_vector_type(8))) unsigned short u16x8;
typedef __attribute__((ext_vector_type(4))) unsigned short u16x4;

__device__ inline unsigned short f2bf(float x) {
    union { float f; unsigned u; } v; v.f = x;
    unsigned r = v.u + 0x7fff + ((v.u >> 16) & 1);   // RNE
    return (unsigned short)(r >> 16);
}

__device__ inline float bf2f(unsigned short u) {
    union { unsigned u; float f; } v; v.u = (unsigned)u << 16;
    return v.f;
}

// ---------------- CSR build ----------------

__global__ void k_zero_fill(int* fill) {
    int i = blockIdx.x * 256 + threadIdx.x;
    if (i < NNODE) fill[i] = 0;
}

__global__ void k_scatter(const int* __restrict__ ei, int* __restrict__ fill,
                          int* __restrict__ csr) {
    int e = blockIdx.x * 256 + threadIdx.x;
    if (e >= NEDGE) return;
    bool is64 = true;
#pragma unroll
    for (int k = 0; k < 8; ++k) is64 = is64 && (ei[2 * k + 1] == 0);
    int s, d;
    if (is64) { s = ei[2 * e]; d = ei[2 * (NEDGE + e)]; }
    else      { s = ei[e];     d = ei[NEDGE + e]; }
    if (s < 0 || s >= NNODE || d < 0 || d >= NNODE) return;
    int pos = atomicAdd(&fill[d], 1);
    if (pos < MAXDEG) csr[d * MAXDEG + pos] = s;
}

// ---------------- W -> MFMA B-fragment layout (bf16) ----------------
// Wt[((kb*4+ko)*128+col)*8+j] = W[kb*32+ko*8+j][col]  (0 beyond KACT)

template <int KB, int KACT>
__global__ void k_prepW(const float* __restrict__ W, unsigned short* __restrict__ Wt) {
    int g = blockIdx.x * 256 + threadIdx.x;          // (kb*4+ko)*128+col
    if (g >= KB * 4 * 128) return;
    int col = g & 127;
    int kq = g >> 7;                                 // kb*4+ko
    u16x8 o;
#pragma unroll
    for (int j = 0; j < 8; ++j) {
        int k = kq * 8 + j;
        o[j] = (k < KACT) ? f2bf(W[(size_t)k * 128 + col]) : (unsigned short)0;
    }
    *(u16x8*)&Wt[(size_t)g * 8] = o;
}

// ---------------- GIN agg 1: A1b[n][96] = bf16(x[n] + sum_j x[j]) ----------------

__global__ void k_agg1b(const float4* __restrict__ x4, const int* __restrict__ fill,
                        const int* __restrict__ csr, unsigned short* __restrict__ A1b) {
    int idx = blockIdx.x * 256 + threadIdx.x;        // NNODE*24
    int n = idx / 24;
    int f4 = idx - n * 24;
    if (f4 >= 21) {                                  // zero pad cols 84..95
        u16x4 z = {0, 0, 0, 0};
        *(u16x4*)&A1b[(size_t)n * 96 + f4 * 4] = z;
        return;
    }
    int deg = fill[n];
    if (deg > MAXDEG) deg = MAXDEG;
    const int* lst = csr + n * MAXDEG;
    float4 s = x4[(size_t)n * 21 + f4];
    int j = 0;
    for (; j + 2 <= deg; j += 2) {
        float4 v0 = x4[(size_t)lst[j] * 21 + f4];
        float4 v1 = x4[(size_t)lst[j + 1] * 21 + f4];
        s.x += v0.x + v1.x; s.y += v0.y + v1.y;
        s.z += v0.z + v1.z; s.w += v0.w + v1.w;
    }
    if (j < deg) {
        float4 v0 = x4[(size_t)lst[j] * 21 + f4];
        s.x += v0.x; s.y += v0.y; s.z += v0.z; s.w += v0.w;
    }
    u16x4 o;
    o[0] = f2bf(s.x); o[1] = f2bf(s.y); o[2] = f2bf(s.z); o[3] = f2bf(s.w);
    *(u16x4*)&A1b[(size_t)n * 96 + f4 * 4] = o;
}

// ---------------- GIN agg 2: A2b[n][128] = bf16(t1b[n] + sum_j t1b[j]) ----------------

__global__ void k_agg2b(const unsigned short* __restrict__ t1b,
                        const int* __restrict__ fill, const int* __restrict__ csr,
                        unsigned short* __restrict__ A2b) {
    int idx = blockIdx.x * 256 + threadIdx.x;        // NNODE*16
    int n = idx >> 4;
    int f8 = idx & 15;
    int deg = fill[n];
    if (deg > MAXDEG) deg = MAXDEG;
    const int* lst = csr + n * MAXDEG;
    u16x8 sv = *(const u16x8*)&t1b[(size_t)n * 128 + f8 * 8];
    float s[8];
#pragma unroll
    for (int e = 0; e < 8; ++e) s[e] = bf2f(sv[e]);
    int j = 0;
    for (; j + 2 <= deg; j += 2) {
        u16x8 v0 = *(const u16x8*)&t1b[(size_t)lst[j] * 128 + f8 * 8];
        u16x8 v1 = *(const u16x8*)&t1b[(size_t)lst[j + 1] * 128 + f8 * 8];
#pragma unroll
        for (int e = 0; e < 8; ++e) s[e] += bf2f(v0[e]) + bf2f(v1[e]);
    }
    if (j < deg) {
        u16x8 v0 = *(const u16x8*)&t1b[(size_t)lst[j] * 128 + f8 * 8];
#pragma unroll
        for (int e = 0; e < 8; ++e) s[e] += bf2f(v0[e]);
    }
    u16x8 o;
#pragma unroll
    for (int e = 0; e < 8; ++e) o[e] = f2bf(s[e]);
    *(u16x8*)&A2b[(size_t)n * 128 + f8 * 8] = o;
}

// ---------------- MFMA GEMM: out[N,128] = A[N,KB*32]bf16 @ Wt + bias (+pe) ----------
// 504 blocks x 128 rows, 4 waves; wave w: rows w*32..w*32+32 (2 frags) x 128 cols.
// A staged in LDS ( [row][k] bf16, XOR ^((row&7)<<4) on 16B units ).
// W frags read from global Wt (L2-resident, B-frag order, coalesced).

template <int KB, bool ADD_PE, bool OUT_F32, bool OUT_BF16>
__global__ __launch_bounds__(256)
void k_gemm_mfma(const unsigned short* __restrict__ A,
                 const unsigned short* __restrict__ Wt,
                 const float* __restrict__ bias, const float* __restrict__ pe,
                 float* __restrict__ of, unsigned short* __restrict__ ob) {
    __shared__ unsigned short As[128 * KB * 32];
    const int t = threadIdx.x;
    const int lane = t & 63;
    const int w = t >> 6;
    const int r = lane & 15;
    const int h = lane >> 4;
    const int row0 = blockIdx.x * 128;

    // stage A tile (128 x KB*32 bf16), 16B units, swizzled
    for (int u = t; u < 128 * KB * 4; u += 256) {
        int row = u / (KB * 4), seg = u - row * (KB * 4);
        u16x8 v = *(const u16x8*)&A[(size_t)(row0 + row) * (KB * 32) + seg * 8];
        *(u16x8*)((char*)As + ((row * (KB * 64) + seg * 16) ^ ((row & 7) << 4))) = v;
    }
    __syncthreads();

    f32x4 acc0[8], acc1[8];
#pragma unroll
    for (int cb = 0; cb < 8; ++cb) {
        acc0[cb] = (f32x4){0.f, 0.f, 0.f, 0.f};
        acc1[cb] = (f32x4){0.f, 0.f, 0.f, 0.f};
    }

#pragma unroll
    for (int kb = 0; kb < KB; ++kb) {
        const int ra = w * 32 + r;
        const int rb = w * 32 + 16 + r;
        bf16x8 pa0 = *(const bf16x8*)((const char*)As +
            ((ra * (KB * 64) + kb * 64 + h * 16) ^ ((ra & 7) << 4)));
        bf16x8 pa1 = *(const bf16x8*)((const char*)As +
            ((rb * (KB * 64) + kb * 64 + h * 16) ^ ((rb & 7) << 4)));
#pragma unroll
        for (int cb = 0; cb < 8; ++cb) {
            bf16x8 wv = *(const bf16x8*)&Wt[(size_t)((kb * 4 + h) * 128 + cb * 16 + r) * 8];
            acc0[cb] = __builtin_amdgcn_mfma_f32_16x16x32_bf16(pa0, wv, acc0[cb], 0, 0, 0);
            acc1[cb] = __builtin_amdgcn_mfma_f32_16x16x32_bf16(pa1, wv, acc1[cb], 0, 0, 0);
        }
    }

    // epilogue (C/D: col = lane&15 = r, row = h*4+i)
#pragma unroll
    for (int cb = 0; cb < 8; ++cb) {
        int col = cb * 16 + r;
        float bv = bias[col];
#pragma unroll
        for (int i = 0; i < 4; ++i) {
            int gr = row0 + w * 32 + h * 4 + i;
            float v = acc0[cb][i] + bv;
            if (ADD_PE) v += pe[(size_t)(gr % SEQ) * 128 + col];
            if (OUT_F32) of[(size_t)gr * 128 + col] = v;
            if (OUT_BF16) ob[(size_t)gr * 128 + col] = f2bf(v);
        }
#pragma unroll
        for (int i = 0; i < 4; ++i) {
            int gr = row0 + w * 32 + 16 + h * 4 + i;
            float v = acc1[cb][i] + bv;
            if (ADD_PE) v += pe[(size_t)(gr % SEQ) * 128 + col];
            if (OUT_F32) of[(size_t)gr * 128 + col] = v;
            if (OUT_BF16) ob[(size_t)gr * 128 + col] = f2bf(v);
        }
    }
}

// ---------------- MFMA flash self-attention (q = k = v) ----------------
// 512 blocks (64 batches x 8 q-tiles of 128 rows), 4 waves; XCD swizzle keeps
// each batch's K/V L2-resident. Register-prefetched K-tile staging.

struct Stg { u16x8 a0, a1, c0, c1; };

__device__ inline Stg load_stage(const unsigned short* qb, int kt, int t) {
    const int kp = t >> 3;
    const int dseg = (t & 7) * 16;
    const int g0 = kt * 64 + kp * 2;
    const u16x8 zz = {0, 0, 0, 0, 0, 0, 0, 0};
    Stg s; s.a0 = zz; s.a1 = zz; s.c0 = zz; s.c1 = zz;
    if (g0 < SEQ) {
        s.a0 = *(const u16x8*)&qb[(size_t)g0 * 128 + dseg];
        s.a1 = *(const u16x8*)&qb[(size_t)g0 * 128 + dseg + 8];
    }
    if (g0 + 1 < SEQ) {
        s.c0 = *(const u16x8*)&qb[(size_t)(g0 + 1) * 128 + dseg];
        s.c1 = *(const u16x8*)&qb[(size_t)(g0 + 1) * 128 + dseg + 8];
    }
    return s;
}

__device__ inline void write_stage(unsigned short* Ks, unsigned short* Vt,
                                   const Stg& s, int t) {
    const int kp = t >> 3;
    const int dseg = (t & 7) * 16;
    const int k0 = kp * 2, k1 = k0 + 1;
    *(u16x8*)((char*)Ks + ((k0 * 256 + dseg * 2) ^ ((k0 & 7) << 4))) = s.a0;
    *(u16x8*)((char*)Ks + ((k0 * 256 + dseg * 2 + 16) ^ ((k0 & 7) << 4))) = s.a1;
    *(u16x8*)((char*)Ks + ((k1 * 256 + dseg * 2) ^ ((k1 & 7) << 4))) = s.c0;
    *(u16x8*)((char*)Ks + ((k1 * 256 + dseg * 2 + 16) ^ ((k1 & 7) << 4))) = s.c1;
#pragma unroll
    for (int j = 0; j < 16; ++j) {
        int d = dseg + j;
        unsigned short lo = (j < 8) ? s.a0[j] : s.a1[j - 8];
        unsigned short hi = (j < 8) ? s.c0[j] : s.c1[j - 8];
        unsigned val = (unsigned)lo | ((unsigned)hi << 16);
        *(unsigned*)((char*)Vt + ((d * 128 + k0 * 2) ^ ((d & 7) << 4)
                                  ^ (((d >> 4) & 3) << 5))) = val;
    }
}

__global__ __launch_bounds__(256, 2)
void k_flash_mfma(const unsigned short* __restrict__ qbf, float* __restrict__ ctx) {
    __shared__ unsigned short Ks[64 * 128];
    __shared__ unsigned short Vt[128 * 64];
    __shared__ unsigned short Pl[4][2][1024];

    const int t = threadIdx.x;
    const int lane = t & 63;
    const int w = t >> 6;
    const int r = lane & 15;
    const int h = lane >> 4;
    const int p = blockIdx.x;
    const int grp = p >> 3;
    const int b = (grp >> 3) * 8 + (p & 7);
    const int qrow0 = (grp & 7) * 128;
    const unsigned short* qb = qbf + (size_t)b * SEQ * HID;

    bf16x8 Qf[2][4];
#pragma unroll
    for (int qa = 0; qa < 2; ++qa) {
        int qrow = qrow0 + w * 32 + qa * 16 + r;
        int qrc = qrow < SEQ ? qrow : SEQ - 1;
#pragma unroll
        for (int ds = 0; ds < 4; ++ds)
            Qf[qa][ds] = *(const bf16x8*)&qb[(size_t)qrc * 128 + ds * 32 + h * 8];
    }

    f32x4 O[2][8];
#pragma unroll
    for (int qa = 0; qa < 2; ++qa)
#pragma unroll
        for (int dt = 0; dt < 8; ++dt) O[qa][dt] = (f32x4){0.f, 0.f, 0.f, 0.f};
    float m_[2][4], l_[2][4];
#pragma unroll
    for (int qa = 0; qa < 2; ++qa)
#pragma unroll
        for (int i = 0; i < 4; ++i) { m_[qa][i] = -1e30f; l_[qa][i] = 0.f; }

    const float scale = 0.08838834764831845f;  // 1/sqrt(128)

    Stg cur = load_stage(qb, 0, t);

    for (int kt = 0; kt < 16; ++kt) {
        __syncthreads();
        write_stage(Ks, Vt, cur, t);
        if (kt < 15) cur = load_stage(qb, kt + 1, t);
        __syncthreads();

        // ---- QK^T ----
        f32x4 S[2][4];
        __builtin_amdgcn_s_setprio(1);
#pragma unroll
        for (int kt4 = 0; kt4 < 4; ++kt4) {
            int key = kt4 * 16 + r;
            f32x4 s0 = (f32x4){0.f, 0.f, 0.f, 0.f};
            f32x4 s1 = (f32x4){0.f, 0.f, 0.f, 0.f};
#pragma unroll
            for (int ds = 0; ds < 4; ++ds) {
                bf16x8 kb = *(const bf16x8*)((const char*)Ks +
                    ((key * 256 + (ds * 32 + h * 8) * 2) ^ ((key & 7) << 4)));
                s0 = __builtin_amdgcn_mfma_f32_16x16x32_bf16(Qf[0][ds], kb, s0, 0, 0, 0);
                s1 = __builtin_amdgcn_mfma_f32_16x16x32_bf16(Qf[1][ds], kb, s1, 0, 0, 0);
            }
            S[0][kt4] = s0; S[1][kt4] = s1;
        }
        __builtin_amdgcn_s_setprio(0);

        // ---- online softmax ----
#pragma unroll
        for (int qa = 0; qa < 2; ++qa) {
            char* Pw = (char*)&Pl[w][qa][0];
            float mx[4] = {-1e30f, -1e30f, -1e30f, -1e30f};
#pragma unroll
            for (int kt4 = 0; kt4 < 4; ++kt4) {
                bool kvalid = (kt * 64 + kt4 * 16 + r) < SEQ;
#pragma unroll
                for (int i = 0; i < 4; ++i) {
                    float v = kvalid ? S[qa][kt4][i] * scale : -1e30f;
                    S[qa][kt4][i] = v;
                    mx[i] = fmaxf(mx[i], v);
                }
            }
#pragma unroll
            for (int i = 0; i < 4; ++i) {
                float v = mx[i];
                v = fmaxf(v, __shfl_xor(v, 1));
                v = fmaxf(v, __shfl_xor(v, 2));
                v = fmaxf(v, __shfl_xor(v, 4));
                v = fmaxf(v, __shfl_xor(v, 8));
                float mn = fmaxf(m_[qa][i], v);
                mx[i] = __expf(m_[qa][i] - mn);     // alpha
                m_[qa][i] = mn;
            }
            float ps[4] = {0.f, 0.f, 0.f, 0.f};
#pragma unroll
            for (int kt4 = 0; kt4 < 4; ++kt4)
#pragma unroll
                for (int i = 0; i < 4; ++i) {
                    float pv = __expf(S[qa][kt4][i] - m_[qa][i]);
                    ps[i] += pv;
                    *(unsigned short*)(Pw + (((h * 4 + i) * 128 + (kt4 * 16 + r) * 2)
                                             ^ (((h * 4 + i) & 7) << 4))) = f2bf(pv);
                }
#pragma unroll
            for (int i = 0; i < 4; ++i) {
                float v = ps[i];
                v += __shfl_xor(v, 1);
                v += __shfl_xor(v, 2);
                v += __shfl_xor(v, 4);
                v += __shfl_xor(v, 8);
                l_[qa][i] = l_[qa][i] * mx[i] + v;
            }
#pragma unroll
            for (int dt = 0; dt < 8; ++dt)
#pragma unroll
                for (int i = 0; i < 4; ++i) O[qa][dt][i] *= mx[i];
        }

        // ---- PV ----
        __builtin_amdgcn_s_setprio(1);
#pragma unroll
        for (int kstep = 0; kstep < 2; ++kstep) {
            bf16x8 pa0 = *(const bf16x8*)((const char*)&Pl[w][0][0] +
                ((r * 128 + (kstep * 32 + h * 8) * 2) ^ ((r & 7) << 4)));
            bf16x8 pa1 = *(const bf16x8*)((const char*)&Pl[w][1][0] +
                ((r * 128 + (kstep * 32 + h * 8) * 2) ^ ((r & 7) << 4)));
#pragma unroll
            for (int dt = 0; dt < 8; ++dt) {
                int d = dt * 16 + r;
                bf16x8 vb = *(const bf16x8*)((const char*)Vt +
                    ((d * 128 + (kstep * 32 + h * 8) * 2) ^ ((d & 7) << 4)
                     ^ (((d >> 4) & 3) << 5)));
                O[0][dt] = __builtin_amdgcn_mfma_f32_16x16x32_bf16(pa0, vb, O[0][dt], 0, 0, 0);
                O[1][dt] = __builtin_amdgcn_mfma_f32_16x16x32_bf16(pa1, vb, O[1][dt], 0, 0, 0);
            }
        }
        __builtin_amdgcn_s_setprio(0);
    }

    // ---- epilogue ----
#pragma unroll
    for (int qa = 0; qa < 2; ++qa)
#pragma unroll
        for (int i = 0; i < 4; ++i) {
            int qq = qrow0 + w * 32 + qa * 16 + h * 4 + i;
            if (qq < SEQ) {
                float inv = 1.f / l_[qa][i];
                size_t base = ((size_t)b * SEQ + qq) * 128 + r;
#pragma unroll
                for (int dt = 0; dt < 8; ++dt)
                    ctx[base + dt * 16] = O[qa][dt][i] * inv;
            }
        }
}

// ---------------- pooling ----------------

__global__ void k_pool(const float* __restrict__ t1, const float* __restrict__ ctx,
                       float* __restrict__ aggr) {
    int bw = blockIdx.x;
    int b = bw / WIN, w = bw - b * WIN;
    int c = threadIdx.x;
    const float* p1 = t1 + ((size_t)(b * SEQ + w * ROI)) * HID + c;
    const float* p2 = ctx + ((size_t)(b * SEQ + w * ROI)) * HID + c;
    float mx1 = -INFINITY, sm1 = 0.f, mx2 = -INFINITY, sm2 = 0.f;
    for (int r = 0; r < ROI; ++r) {
        float a = p1[r * HID]; mx1 = fmaxf(mx1, a); sm1 += a;
        float d = p2[r * HID]; mx2 = fmaxf(mx2, d); sm2 += d;
    }
    float* o = aggr + (size_t)b * 6144 + w * 512;
    o[c] = mx1;
    o[128 + c] = sm1 * (1.f / 84.f);
    o[256 + c] = mx2;
    o[384 + c] = sm2 * (1.f / 84.f);
}

// ---------------- fc1 split-K ----------------

#define KSPLIT 48

__global__ __launch_bounds__(256)
void k_fc1_partial(const float* __restrict__ aggr, const float* __restrict__ W,
                   float* __restrict__ part) {
    __shared__ float As[64 * 132];
    const int t = threadIdx.x;
    const int cb = (blockIdx.x & 7) * 64;
    const int ks = blockIdx.x >> 3;
    const int kb = ks * 128;

    {
        int r = t >> 2, seg = (t & 3) * 32;
#pragma unroll
        for (int i = 0; i < 8; ++i)
            *(float4*)&As[r * 132 + seg + i * 4] =
                *(const float4*)&aggr[(size_t)r * 6144 + kb + seg + i * 4];
    }
    __syncthreads();

    const int r0 = (t >> 4) << 2;
    const int c0 = (t & 15) << 2;
    float acc[4][4];
#pragma unroll
    for (int i = 0; i < 4; ++i)
#pragma unroll
        for (int j = 0; j < 4; ++j) acc[i][j] = 0.f;

#pragma unroll 4
    for (int kk = 0; kk < 128; ++kk) {
        float4 w = *(const float4*)&W[(size_t)(kb + kk) * 512 + cb + c0];
#pragma unroll
        for (int i = 0; i < 4; ++i) {
            float a = As[(r0 + i) * 132 + kk];
            acc[i][0] += a * w.x; acc[i][1] += a * w.y;
            acc[i][2] += a * w.z; acc[i][3] += a * w.w;
        }
    }

    float* pp = part + (size_t)ks * (64 * 512);
#pragma unroll
    for (int i = 0; i < 4; ++i)
        *(float4*)&pp[(size_t)(r0 + i) * 512 + cb + c0] = *(float4*)&acc[i][0];
}

__global__ void k_fc1_reduce(const float* __restrict__ part,
                             const float* __restrict__ bias,
                             const float* __restrict__ g, const float* __restrict__ bb,
                             const float* __restrict__ m, const float* __restrict__ v,
                             float* __restrict__ h1) {
    int i = blockIdx.x * 256 + threadIdx.x;
    if (i >= 64 * 512) return;
    float s = 0.f;
    for (int ks = 0; ks < KSPLIT; ++ks) s += part[ks * 32768 + i];
    int c = i & 511;
    float x = s + bias[c];
    float sl = x / (1.f + __expf(-x));
    h1[i] = (sl - m[c]) * rsqrtf(v[c] + 1e-5f) * g[c] + bb[c];
}

// ---------------- head ----------------

__global__ __launch_bounds__(256)
void k_head(const float* __restrict__ h1,
            const float* __restrict__ fc2w, const float* __restrict__ fc2b,
            const float* __restrict__ g2, const float* __restrict__ b2,
            const float* __restrict__ m2, const float* __restrict__ v2,
            const float* __restrict__ fc3w, const float* __restrict__ fc3b,
            float* __restrict__ out) {
    __shared__ float row[512];
    __shared__ float red[8 * 32];
    __shared__ float h2[32];
    const int b = blockIdx.x, t = threadIdx.x;
    row[t] = h1[(size_t)b * 512 + t];
    row[t + 256] = h1[(size_t)b * 512 + 256 + t];
    __syncthreads();
    {
        int c = t & 31, part = t >> 5;
        float s = 0.f;
        for (int k = part * 64; k < part * 64 + 64; ++k) s += row[k] * fc2w[k * 32 + c];
        red[part * 32 + c] = s;
    }
    __syncthreads();
    if (t < 32) {
        float vv = 0.f;
        for (int p = 0; p < 8; ++p) vv += red[p * 32 + t];
        vv += fc2b[t];
        float sl = vv / (1.f + __expf(-vv));
        h2[t] = (sl - m2[t]) * rsqrtf(v2[t] + 1e-5f) * g2[t] + b2[t];
    }
    __syncthreads();
    if (t == 0) {
        float l0 = fc3b[0], l1 = fc3b[1];
        for (int k = 0; k < 32; ++k) { l0 += h2[k] * fc3w[k * 2]; l1 += h2[k] * fc3w[k * 2 + 1]; }
        float mx = fmaxf(l0, l1);
        float e0 = __expf(l0 - mx), e1 = __expf(l1 - mx);
        float inv = 1.f / (e0 + e1);
        out[b * 2] = e0 * inv;
        out[b * 2 + 1] = e1 * inv;
    }
}

// ---------------- launch ----------------

extern "C" void kernel_launch(void* const* d_in, const int* in_sizes, int n_in,
                              void* d_out, int out_size, void* d_ws, size_t ws_size,
                              hipStream_t stream) {
    (void)in_sizes; (void)n_in; (void)out_size;

    const float* x    = (const float*)d_in[0];
    const int*   ei   = (const int*)d_in[1];
    const float* pe   = (const float*)d_in[2];
    const float* W1   = (const float*)d_in[3];
    const float* b1   = (const float*)d_in[4];
    const float* W2   = (const float*)d_in[5];
    const float* b2   = (const float*)d_in[6];
    const float* fc1w = (const float*)d_in[7];
    const float* fc1b = (const float*)d_in[8];
    const float* fc2w = (const float*)d_in[9];
    const float* fc2b = (const float*)d_in[10];
    const float* fc3w = (const float*)d_in[11];
    const float* fc3b = (const float*)d_in[12];
    const float* bn1g = (const float*)d_in[13];
    const float* bn1b = (const float*)d_in[14];
    const float* bn1m = (const float*)d_in[15];
    const float* bn1v = (const float*)d_in[16];
    const float* bn2g = (const float*)d_in[17];
    const float* bn2b = (const float*)d_in[18];
    const float* bn2m = (const float*)d_in[19];
    const float* bn2v = (const float*)d_in[20];
    float* out = (float*)d_out;

    char* ws = (char*)d_ws;
    unsigned short* A1b  = (unsigned short*)(ws + 0);          // N*96*2  = 12,386,304
    float*          t1   = (float*)(ws + 12386304);            // N*128*4 = 33,030,144
    unsigned short* t1b  = (unsigned short*)(ws + 45416448);   // N*128*2 = 16,515,072
    unsigned short* A2b  = (unsigned short*)(ws + 61931520);   // 16,515,072
    unsigned short* qbf  = (unsigned short*)(ws + 78446592);   // 16,515,072
    float*          ctx  = (float*)(ws + 94961664);            // 33,030,144
    float*          aggr = (float*)(ws + 127991808);           // 1,572,864
    float*          h1   = (float*)(ws + 129564672);           // 131,072
    int*            fill = (int*)  (ws + 129695744);           // 258,048
    int*            csr  = (int*)  (ws + 129953792);           // 16,515,072
    unsigned short* Wt1  = (unsigned short*)(ws + 146468864);  // 24,576
    unsigned short* Wt2  = (unsigned short*)(ws + 146493440);  // 32,768
    float*          part = (float*)A1b;   // fc1 partials (6.3MB) alias A1b (dead by then)
    if (ws_size < 146526208ull) return;

    k_zero_fill<<<(NNODE + 255) / 256, 256, 0, stream>>>(fill);
    k_scatter<<<(NEDGE + 255) / 256, 256, 0, stream>>>(ei, fill, csr);
    k_prepW<3, 84><<<6, 256, 0, stream>>>(W1, Wt1);
    k_prepW<4, 128><<<8, 256, 0, stream>>>(W2, Wt2);
    k_agg1b<<<(NNODE * 24) / 256, 256, 0, stream>>>((const float4*)x, fill, csr, A1b);
    k_gemm_mfma<3, false, true, true><<<NNODE / 128, 256, 0, stream>>>(
        A1b, Wt1, b1, nullptr, t1, t1b);
    k_agg2b<<<(NNODE * 16) / 256, 256, 0, stream>>>(t1b, fill, csr, A2b);
    k_gemm_mfma<4, true, false, true><<<NNODE / 128, 256, 0, stream>>>(
        A2b, Wt2, b2, pe, nullptr, qbf);
    k_flash_mfma<<<BATCH * 8, 256, 0, stream>>>(qbf, ctx);
    k_pool<<<BATCH * WIN, 128, 0, stream>>>(t1, ctx, aggr);
    k_fc1_partial<<<8 * KSPLIT, 256, 0, stream>>>(aggr, fc1w, part);
    k_fc1_reduce<<<128, 256, 0, stream>>>(part, fc1b, bn1g, bn1b, bn1m, bn1v, h1);
    k_head<<<BATCH, 256, 0, stream>>>(h1, fc2w, fc2b, bn2g, bn2b, bn2m, bn2v,
                                      fc3w, fc3b, out);
}